// Round 4
// baseline (860.912 us; speedup 1.0000x reference)
//
#include <hip/hip_runtime.h>
#include <hip/hip_bf16.h>

#define NNODES 50000
#define DIM 128
#define NREL 3
#define NEDGE 800000
#define NCHUNK 25            // ceil(NNODES / 2048) scan chunks
// K of the fused GEMM = DIM (self) + NREL*DIM (means) = 512

// ---------------------------------------------------------------------------
// 1. Fold weights:  Wf[l] (512x128) = [ W_self@S ; W_neigh@Wm_0 ; W_neigh@Wm_1 ; W_neigh@Wm_2 ]
//    with S = sum_r Wm_r.   bias c[l] = b_self@S + bm.
//    Derivation: cat(embs)@Wm = Σ_r emb_r@Wm_r ; emb_r = h@W_self + b_self + mean_r@W_neigh
//    grid (513, L), 128 threads; block 512 of x computes bias.
// ---------------------------------------------------------------------------
__global__ void prep_weights(const float* __restrict__ Wself, const float* __restrict__ bself,
                             const float* __restrict__ Wneigh, const float* __restrict__ Wm,
                             const float* __restrict__ bm,
                             float* __restrict__ Wf, float* __restrict__ bias) {
    const int l = blockIdx.y;
    const int i = blockIdx.x;          // 0..512 (512 => bias row)
    const int j = threadIdx.x;         // 0..127
    const float* Wm_l = Wm + (size_t)l * 3 * DIM * DIM;
    if (i == 512) {
        float acc = bm[l * DIM + j];
        for (int k = 0; k < DIM; ++k) {
            float s = Wm_l[k * DIM + j] + Wm_l[(DIM + k) * DIM + j] + Wm_l[(2 * DIM + k) * DIM + j];
            acc += bself[l * DIM + k] * s;
        }
        bias[l * DIM + j] = acc;
        return;
    }
    float acc = 0.f;
    if (i < DIM) {                     // W_self @ S
        const float* A = Wself + (size_t)l * DIM * DIM + (size_t)i * DIM;
        for (int k = 0; k < DIM; ++k) {
            float s = Wm_l[k * DIM + j] + Wm_l[(DIM + k) * DIM + j] + Wm_l[(2 * DIM + k) * DIM + j];
            acc += A[k] * s;
        }
    } else {                           // W_neigh @ Wm_r  (row a of block r)
        const int r = (i - DIM) >> 7;
        const int a = (i - DIM) & 127;
        const float* A = Wneigh + (size_t)l * DIM * DIM + (size_t)a * DIM;
        const float* B = Wm_l + (size_t)r * DIM * DIM;
        for (int k = 0; k < DIM; ++k) acc += A[k] * B[k * DIM + j];
    }
    Wf[(size_t)l * 512 * DIM + (size_t)i * DIM + j] = acc;
}

// ---------------------------------------------------------------------------
// 2. CSR build (per relation): degree histogram -> hierarchical scan -> fill
// ---------------------------------------------------------------------------
__global__ void deg_hist(const int* __restrict__ dst, int* __restrict__ degs) {
    const int e = blockIdx.x * 256 + threadIdx.x;
    const int r = blockIdx.y;
    if (e < NEDGE) atomicAdd(&degs[r * NNODES + dst[(size_t)r * NEDGE + e]], 1);
}

// per-chunk (2048 nodes) inclusive scan; writes rptr[idx+1] (chunk-local) + chunk total
__global__ __launch_bounds__(256) void scan_local(const int* __restrict__ degs,
                                                  int* __restrict__ rptr,
                                                  int* __restrict__ bsum) {
    const int r = blockIdx.y;
    const int b = blockIdx.x;
    const int t = threadIdx.x;
    const int base = b * 2048;
    const int* d = degs + (size_t)r * NNODES;
    int v[8];
    int s = 0;
    #pragma unroll
    for (int i = 0; i < 8; ++i) {
        const int idx = base + t * 8 + i;
        v[i] = (idx < NNODES) ? d[idx] : 0;
        s += v[i];
        v[i] = s;                        // thread-local inclusive
    }
    // wave-inclusive scan of per-thread totals
    const int lane = t & 63;
    int wsc = s;
    #pragma unroll
    for (int off = 1; off < 64; off <<= 1) {
        int u = __shfl_up(wsc, off);
        if (lane >= off) wsc += u;
    }
    __shared__ int wtot[4];
    const int w = t >> 6;
    if (lane == 63) wtot[w] = wsc;
    __syncthreads();
    int wpre = 0;
    for (int i = 0; i < w; ++i) wpre += wtot[i];
    const int thrpre = wpre + wsc - s;   // exclusive prefix of this thread within chunk
    int* p = rptr + (size_t)r * (NNODES + 1);
    #pragma unroll
    for (int i = 0; i < 8; ++i) {
        const int idx = base + t * 8 + i;
        if (idx < NNODES) p[idx + 1] = thrpre + v[i];
    }
    if (t == 255) bsum[r * NCHUNK + b] = wpre + wsc;   // chunk total
}

// exclusive-scan the 25 chunk totals per relation (in place); trivial size
__global__ void scan_bsums(int* __restrict__ bsum) {
    const int r = threadIdx.x;
    if (r >= NREL) return;
    int acc = 0;
    for (int b = 0; b < NCHUNK; ++b) {
        const int t = bsum[r * NCHUNK + b];
        bsum[r * NCHUNK + b] = acc;
        acc += t;
    }
}

__global__ __launch_bounds__(256) void add_off(const int* __restrict__ bsum,
                                               int* __restrict__ rptr) {
    const int r = blockIdx.y;
    const int b = blockIdx.x;
    const int off = bsum[r * NCHUNK + b];
    int* p = rptr + (size_t)r * (NNODES + 1);
    if (b == 0 && threadIdx.x == 0) p[0] = 0;
    #pragma unroll
    for (int i = 0; i < 8; ++i) {
        const int idx = b * 2048 + threadIdx.x * 8 + i;
        if (idx < NNODES) p[idx + 1] += off;
    }
}

__global__ void fill_csr(const int* __restrict__ src, const int* __restrict__ dst,
                         const int* __restrict__ rptr, int* __restrict__ cursor,
                         int* __restrict__ col) {
    const int e = blockIdx.x * 256 + threadIdx.x;
    const int r = blockIdx.y;
    if (e >= NEDGE) return;
    const int d = dst[(size_t)r * NEDGE + e];
    const int pos = rptr[(size_t)r * (NNODES + 1) + d] + atomicAdd(&cursor[r * NNODES + d], 1);
    col[(size_t)r * NEDGE + pos] = src[(size_t)r * NEDGE + e];
}

// ---------------------------------------------------------------------------
// 3. Pull aggregation: one wave per (node, relation). Lanes 0-31 / 32-63 each
//    handle one edge (full 512B row as 32 x float4). Edge loop unrolled by 8:
//    4 independent dwordx4 loads in flight per half-wave (mask-multiply for
//    the tail; masked loads hit row 0, valid & L1-hot). Shfl indices <= 63 by
//    construction (j<=56 => j+6+hi<=63).
//    Writes mean_r into Xm[n][r*128 .. +128]  (Xm: [N, 384]).
// ---------------------------------------------------------------------------
__global__ __launch_bounds__(256) void aggregate(const float* __restrict__ H,
                                                 const int* __restrict__ rptr,
                                                 const int* __restrict__ col,
                                                 float* __restrict__ Xm) {
    const int wid = (blockIdx.x * 256 + threadIdx.x) >> 6;
    const int lane = threadIdx.x & 63;
    if (wid >= NREL * NNODES) return;
    const int r = wid / NNODES;
    const int n = wid - r * NNODES;
    const int e0 = rptr[(size_t)r * (NNODES + 1) + n];
    const int e1 = rptr[(size_t)r * (NNODES + 1) + n + 1];
    const int* cl = col + (size_t)r * NEDGE;
    const int hi = lane >> 5;            // which edge of a pair
    const int hl = lane & 31;            // lane within half (covers 4 cols)
    float4 acc = make_float4(0.f, 0.f, 0.f, 0.f);
    for (int e = e0; e < e1; e += 64) {
        const int ce = (e + lane < e1) ? cl[e + lane] : 0;
        const int cnt = min(64, e1 - e);
        for (int j = 0; j < cnt; j += 8) {
            // edges j..j+7: each half-wave takes 4 (even/odd split by hi)
            int   sidx[4];
            float msk[4];
            #pragma unroll
            for (int u = 0; u < 4; ++u) {
                const int eid = j + 2 * u + hi;
                sidx[u] = __shfl(ce, eid);
                msk[u] = (eid < cnt) ? 1.f : 0.f;
            }
            #pragma unroll
            for (int u = 0; u < 4; ++u) {
                const float4 v = *reinterpret_cast<const float4*>(
                    H + (size_t)sidx[u] * DIM + 4 * hl);
                acc.x += v.x * msk[u]; acc.y += v.y * msk[u];
                acc.z += v.z * msk[u]; acc.w += v.w * msk[u];
            }
        }
    }
    acc.x += __shfl_xor(acc.x, 32);
    acc.y += __shfl_xor(acc.y, 32);
    acc.z += __shfl_xor(acc.z, 32);
    acc.w += __shfl_xor(acc.w, 32);
    if (hi == 0) {
        const float inv = 1.f / (float)max(e1 - e0, 1);
        float4 o;
        o.x = acc.x * inv; o.y = acc.y * inv; o.z = acc.z * inv; o.w = acc.w * inv;
        *reinterpret_cast<float4*>(Xm + (size_t)n * (NREL * DIM) + r * DIM + 4 * hl) = o;
    }
}

// ---------------------------------------------------------------------------
// 4. Fused GEMM:  Out = act( [Hsrc | Xm] (Nx512) @ Wf (512x128) + bias )
//    fp32 vector-FMA tiled GEMM, BM=128, BN=128(all), BK=32, 256 thr, 8x8/thr.
//    IN-PLACE SAFE (Hsrc may equal Out): each block reads A-rows only from its
//    own [m0, m0+128) tile; all reads precede the epilogue store; no block
//    reads another block's output rows.
// ---------------------------------------------------------------------------
template <bool RELU>
__global__ __launch_bounds__(256) void gemm_fused(const float* __restrict__ Hsrc,
                                                  const float* __restrict__ Xm,
                                                  const float* __restrict__ Wf,
                                                  const float* __restrict__ bias,
                                                  float* __restrict__ Out) {
    __shared__ float As[32][132];   // A tile transposed: As[k][row]
    __shared__ float Bs[32][132];   // B tile: Bs[k][col]
    const int m0 = blockIdx.x * 128;
    const int tid = threadIdx.x;
    const int tx = tid & 15;
    const int ty = tid >> 4;
    float acc[2][2][4][4];
    #pragma unroll
    for (int a = 0; a < 2; ++a)
        #pragma unroll
        for (int b = 0; b < 2; ++b)
            #pragma unroll
            for (int i = 0; i < 4; ++i)
                #pragma unroll
                for (int j = 0; j < 4; ++j) acc[a][b][i][j] = 0.f;

    for (int kt = 0; kt < 16; ++kt) {
        const int k0 = kt * 32;
        // ---- load A tile (rows m0..m0+128, cols k0..k0+32), transpose into LDS
        #pragma unroll
        for (int i = 0; i < 4; ++i) {
            const int fidx = tid + i * 256;
            const int row = fidx >> 3;
            const int c0 = (fidx & 7) * 4;
            const int gr = m0 + row;
            float4 v = make_float4(0.f, 0.f, 0.f, 0.f);
            if (gr < NNODES) {
                const int gc = k0 + c0;
                const float* sp = (gc < DIM)
                    ? (Hsrc + (size_t)gr * DIM + gc)
                    : (Xm + (size_t)gr * (NREL * DIM) + (gc - DIM));
                v = *reinterpret_cast<const float4*>(sp);
            }
            As[c0 + 0][row] = v.x; As[c0 + 1][row] = v.y;
            As[c0 + 2][row] = v.z; As[c0 + 3][row] = v.w;
        }
        // ---- load B tile (Wf rows k0..k0+32, all 128 cols)
        #pragma unroll
        for (int i = 0; i < 4; ++i) {
            const int fidx = tid + i * 256;
            const int row = fidx >> 5;
            const int c0 = (fidx & 31) * 4;
            const float4 v = *reinterpret_cast<const float4*>(Wf + (size_t)(k0 + row) * DIM + c0);
            *reinterpret_cast<float4*>(&Bs[row][c0]) = v;
        }
        __syncthreads();
        #pragma unroll
        for (int k = 0; k < 32; ++k) {
            float a[2][4], b[2][4];
            *reinterpret_cast<float4*>(a[0]) = *reinterpret_cast<const float4*>(&As[k][ty * 4]);
            *reinterpret_cast<float4*>(a[1]) = *reinterpret_cast<const float4*>(&As[k][64 + ty * 4]);
            *reinterpret_cast<float4*>(b[0]) = *reinterpret_cast<const float4*>(&Bs[k][tx * 4]);
            *reinterpret_cast<float4*>(b[1]) = *reinterpret_cast<const float4*>(&Bs[k][64 + tx * 4]);
            #pragma unroll
            for (int rh = 0; rh < 2; ++rh)
                #pragma unroll
                for (int ch = 0; ch < 2; ++ch)
                    #pragma unroll
                    for (int i2 = 0; i2 < 4; ++i2)
                        #pragma unroll
                        for (int j2 = 0; j2 < 4; ++j2)
                            acc[rh][ch][i2][j2] += a[rh][i2] * b[ch][j2];
        }
        __syncthreads();
    }
    // ---- epilogue: bias, optional ReLU, store
    #pragma unroll
    for (int rh = 0; rh < 2; ++rh) {
        #pragma unroll
        for (int i2 = 0; i2 < 4; ++i2) {
            const int row = m0 + rh * 64 + ty * 4 + i2;
            if (row >= NNODES) continue;
            #pragma unroll
            for (int ch = 0; ch < 2; ++ch) {
                const int c0 = ch * 64 + tx * 4;
                float4 v;
                v.x = acc[rh][ch][i2][0] + bias[c0 + 0];
                v.y = acc[rh][ch][i2][1] + bias[c0 + 1];
                v.z = acc[rh][ch][i2][2] + bias[c0 + 2];
                v.w = acc[rh][ch][i2][3] + bias[c0 + 3];
                if (RELU) {
                    v.x = fmaxf(v.x, 0.f); v.y = fmaxf(v.y, 0.f);
                    v.z = fmaxf(v.z, 0.f); v.w = fmaxf(v.w, 0.f);
                }
                *reinterpret_cast<float4*>(Out + (size_t)row * DIM + c0) = v;
            }
        }
    }
}

// ---------------------------------------------------------------------------
extern "C" void kernel_launch(void* const* d_in, const int* in_sizes, int n_in,
                              void* d_out, int out_size, void* d_ws, size_t ws_size,
                              hipStream_t stream) {
    const float* feats  = (const float*)d_in[0];
    const int*   src    = (const int*)d_in[1];
    const int*   dst    = (const int*)d_in[2];
    const float* Wself  = (const float*)d_in[3];
    const float* bself  = (const float*)d_in[4];
    const float* Wneigh = (const float*)d_in[5];
    const float* Wm     = (const float*)d_in[6];
    const float* bmv    = (const float*)d_in[7];
    float* out = (float*)d_out;

    // workspace carve-up (4-byte units); H1 lives in d_out (in-place layer 1)
    float* ws   = (float*)d_ws;
    float* Wf   = ws;                        // 2*512*128          = 131072
    float* bias = Wf + 131072;               // 2*128              = 256
    int*   rptr = (int*)(bias + 256);        // 3*(N+1) pad        = 150016
    int*   degs = rptr + 150016;             // 3*N                = 150000
    int*   curs = degs + 150000;             // 3*N                = 150000
    int*   bsum = curs + 150000;             // 3*25 pad           = 80
    int*   col  = bsum + 80;                 // 3*E                = 2400000
    float* Xm   = (float*)(col + 2400000);   // N*384              = 19200000
    float* H1   = out;                       // layer-0 output -> d_out (25.6 MB saved)
    // total ~= 88.7 MB

    // zero degree histogram + cursors (contiguous)
    hipMemsetAsync(degs, 0, (size_t)(150000 + 150000) * sizeof(int), stream);

    // fold weights
    prep_weights<<<dim3(513, 2), 128, 0, stream>>>(Wself, bself, Wneigh, Wm, bmv, Wf, bias);

    // CSR build (shared by both layers)
    deg_hist<<<dim3(NEDGE / 256, NREL), 256, 0, stream>>>(dst, degs);
    scan_local<<<dim3(NCHUNK, NREL), 256, 0, stream>>>(degs, rptr, bsum);
    scan_bsums<<<1, 64, 0, stream>>>(bsum);
    add_off<<<dim3(NCHUNK, NREL), 256, 0, stream>>>(bsum, rptr);
    fill_csr<<<dim3(NEDGE / 256, NREL), 256, 0, stream>>>(src, dst, rptr, curs, col);

    const int aggBlocks  = (NREL * NNODES) / 4;          // 4 waves/block, exact
    const int gemmBlocks = (NNODES + 127) / 128;         // 391

    // layer 0
    aggregate<<<aggBlocks, 256, 0, stream>>>(feats, rptr, col, Xm);
    gemm_fused<true><<<gemmBlocks, 256, 0, stream>>>(feats, Xm, Wf, bias, H1);

    // layer 1 (GEMM in place: Hsrc == Out == d_out)
    aggregate<<<aggBlocks, 256, 0, stream>>>(H1, rptr, col, Xm);
    gemm_fused<false><<<gemmBlocks, 256, 0, stream>>>(H1, Xm, Wf + 65536, bias + 128, out);
}

// Round 5
// 716.784 us; speedup vs baseline: 1.2011x; 1.2011x over previous
//
#include <hip/hip_runtime.h>
#include <hip/hip_bf16.h>

#define NNODES 50000
#define DIM 128
#define NREL 3
#define NEDGE 800000
#define NCHUNK 25            // ceil(NNODES / 2048) scan chunks
// K of the fused GEMM = DIM (self) + NREL*DIM (means) = 512

typedef __attribute__((ext_vector_type(8))) short bf16x8;   // 8 bf16 in 4 VGPRs
typedef __attribute__((ext_vector_type(4))) float f32x4;    // MFMA accumulator

__device__ __forceinline__ ushort f2bf(float x) {           // RNE fp32->bf16
    unsigned u = __float_as_uint(x);
    return (ushort)((u + 0x7fffu + ((u >> 16) & 1u)) >> 16);
}
__device__ __forceinline__ float bf2f(ushort h) {
    return __uint_as_float(((unsigned)h) << 16);
}

// ---------------------------------------------------------------------------
// 1. Fold weights:  Wf[l] (512x128) = [ W_self@S ; W_neigh@Wm_0 ; W_neigh@Wm_1 ; W_neigh@Wm_2 ]
//    with S = sum_r Wm_r.   bias c[l] = b_self@S + bm.
//    (cat(embs)@Wm = Σ_r emb_r@Wm_r ; emb_r = h@W_self + b_self + mean_r@W_neigh)
// ---------------------------------------------------------------------------
__global__ void prep_weights(const float* __restrict__ Wself, const float* __restrict__ bself,
                             const float* __restrict__ Wneigh, const float* __restrict__ Wm,
                             const float* __restrict__ bm,
                             float* __restrict__ Wf, float* __restrict__ bias) {
    const int l = blockIdx.y;
    const int i = blockIdx.x;          // 0..512 (512 => bias row)
    const int j = threadIdx.x;         // 0..127
    const float* Wm_l = Wm + (size_t)l * 3 * DIM * DIM;
    if (i == 512) {
        float acc = bm[l * DIM + j];
        for (int k = 0; k < DIM; ++k) {
            float s = Wm_l[k * DIM + j] + Wm_l[(DIM + k) * DIM + j] + Wm_l[(2 * DIM + k) * DIM + j];
            acc += bself[l * DIM + k] * s;
        }
        bias[l * DIM + j] = acc;
        return;
    }
    float acc = 0.f;
    if (i < DIM) {                     // W_self @ S
        const float* A = Wself + (size_t)l * DIM * DIM + (size_t)i * DIM;
        for (int k = 0; k < DIM; ++k) {
            float s = Wm_l[k * DIM + j] + Wm_l[(DIM + k) * DIM + j] + Wm_l[(2 * DIM + k) * DIM + j];
            acc += A[k] * s;
        }
    } else {                           // W_neigh @ Wm_r  (row a of block r)
        const int r = (i - DIM) >> 7;
        const int a = (i - DIM) & 127;
        const float* A = Wneigh + (size_t)l * DIM * DIM + (size_t)a * DIM;
        const float* B = Wm_l + (size_t)r * DIM * DIM;
        for (int k = 0; k < DIM; ++k) acc += A[k] * B[k * DIM + j];
    }
    Wf[(size_t)l * 512 * DIM + (size_t)i * DIM + j] = acc;
}

// ---------------------------------------------------------------------------
// 1b. Split Wf into hi/lo bf16 in MFMA B-fragment order:
//     off = (((kt*8+ct)*4+kgrp)*16+col)*8 + e   (kt=k>>5, kgrp=(k&31)>>3, e=k&7,
//     ct=j>>4, col=j&15).  One dwordx4 per lane = one full B-frag.
// ---------------------------------------------------------------------------
__global__ void wsplit(const float* __restrict__ Wf, ushort* __restrict__ Whi,
                       ushort* __restrict__ Wlo) {
    const int idx = blockIdx.x * 256 + threadIdx.x;     // 2*512*128 = 131072
    if (idx >= 2 * 512 * DIM) return;
    const int l = idx >> 16;
    const int rem = idx & 65535;
    const int k = rem >> 7, j = rem & 127;
    const float w = Wf[idx];
    const ushort h = f2bf(w);
    const ushort lo = f2bf(w - bf2f(h));
    const int kt = k >> 5, kl = k & 31, kg = kl >> 3, e = kl & 7;
    const int ct = j >> 4, col = j & 15;
    const size_t off = (size_t)l * 65536 + ((((kt * 8 + ct) * 4 + kg) * 16 + col) * 8 + e);
    Whi[off] = h;
    Wlo[off] = lo;
}

// ---------------------------------------------------------------------------
// 2. CSR build (per relation): degree histogram -> hierarchical scan -> fill
// ---------------------------------------------------------------------------
__global__ void deg_hist(const int* __restrict__ dst, int* __restrict__ degs) {
    const int e = blockIdx.x * 256 + threadIdx.x;
    const int r = blockIdx.y;
    if (e < NEDGE) atomicAdd(&degs[r * NNODES + dst[(size_t)r * NEDGE + e]], 1);
}

__global__ __launch_bounds__(256) void scan_local(const int* __restrict__ degs,
                                                  int* __restrict__ rptr,
                                                  int* __restrict__ bsum) {
    const int r = blockIdx.y;
    const int b = blockIdx.x;
    const int t = threadIdx.x;
    const int base = b * 2048;
    const int* d = degs + (size_t)r * NNODES;
    int v[8];
    int s = 0;
    #pragma unroll
    for (int i = 0; i < 8; ++i) {
        const int idx = base + t * 8 + i;
        v[i] = (idx < NNODES) ? d[idx] : 0;
        s += v[i];
        v[i] = s;
    }
    const int lane = t & 63;
    int wsc = s;
    #pragma unroll
    for (int off = 1; off < 64; off <<= 1) {
        int u = __shfl_up(wsc, off);
        if (lane >= off) wsc += u;
    }
    __shared__ int wtot[4];
    const int w = t >> 6;
    if (lane == 63) wtot[w] = wsc;
    __syncthreads();
    int wpre = 0;
    for (int i = 0; i < w; ++i) wpre += wtot[i];
    const int thrpre = wpre + wsc - s;
    int* p = rptr + (size_t)r * (NNODES + 1);
    #pragma unroll
    for (int i = 0; i < 8; ++i) {
        const int idx = base + t * 8 + i;
        if (idx < NNODES) p[idx + 1] = thrpre + v[i];
    }
    if (t == 255) bsum[r * NCHUNK + b] = wpre + wsc;
}

__global__ void scan_bsums(int* __restrict__ bsum) {
    const int r = threadIdx.x;
    if (r >= NREL) return;
    int acc = 0;
    for (int b = 0; b < NCHUNK; ++b) {
        const int t = bsum[r * NCHUNK + b];
        bsum[r * NCHUNK + b] = acc;
        acc += t;
    }
}

__global__ __launch_bounds__(256) void add_off(const int* __restrict__ bsum,
                                               int* __restrict__ rptr) {
    const int r = blockIdx.y;
    const int b = blockIdx.x;
    const int off = bsum[r * NCHUNK + b];
    int* p = rptr + (size_t)r * (NNODES + 1);
    if (b == 0 && threadIdx.x == 0) p[0] = 0;
    #pragma unroll
    for (int i = 0; i < 8; ++i) {
        const int idx = b * 2048 + threadIdx.x * 8 + i;
        if (idx < NNODES) p[idx + 1] += off;
    }
}

__global__ void fill_csr(const int* __restrict__ src, const int* __restrict__ dst,
                         const int* __restrict__ rptr, int* __restrict__ cursor,
                         int* __restrict__ col) {
    const int e = blockIdx.x * 256 + threadIdx.x;
    const int r = blockIdx.y;
    if (e >= NEDGE) return;
    const int d = dst[(size_t)r * NEDGE + e];
    const int pos = rptr[(size_t)r * (NNODES + 1) + d] + atomicAdd(&cursor[r * NNODES + d], 1);
    col[(size_t)r * NEDGE + pos] = src[(size_t)r * NEDGE + e];
}

// ---------------------------------------------------------------------------
// 3. Pull aggregation: one wave per (node, relation). Half-wave per edge-row
//    (32 x float4 = 512B). Edge loop unrolled by 16 => 8 independent dwordx4
//    in flight per half-wave (masked tails read row 0, valid & hot).
// ---------------------------------------------------------------------------
__global__ __launch_bounds__(256) void aggregate(const float* __restrict__ H,
                                                 const int* __restrict__ rptr,
                                                 const int* __restrict__ col,
                                                 float* __restrict__ Xm) {
    const int wid = (blockIdx.x * 256 + threadIdx.x) >> 6;
    const int lane = threadIdx.x & 63;
    if (wid >= NREL * NNODES) return;
    const int r = wid / NNODES;
    const int n = wid - r * NNODES;
    const int e0 = rptr[(size_t)r * (NNODES + 1) + n];
    const int e1 = rptr[(size_t)r * (NNODES + 1) + n + 1];
    const int* cl = col + (size_t)r * NEDGE;
    const int hi = lane >> 5;
    const int hl = lane & 31;
    float4 acc = make_float4(0.f, 0.f, 0.f, 0.f);
    for (int e = e0; e < e1; e += 64) {
        const int ce = (e + lane < e1) ? cl[e + lane] : 0;
        const int cnt = min(64, e1 - e);
        for (int j = 0; j < cnt; j += 16) {
            int   sidx[8];
            float msk[8];
            #pragma unroll
            for (int u = 0; u < 8; ++u) {
                const int eid = j + 2 * u + hi;          // <= 63 by construction
                sidx[u] = __shfl(ce, eid);
                msk[u] = (eid < cnt) ? 1.f : 0.f;
            }
            #pragma unroll
            for (int u = 0; u < 8; ++u) {
                const float4 v = *reinterpret_cast<const float4*>(
                    H + (size_t)sidx[u] * DIM + 4 * hl);
                acc.x += v.x * msk[u]; acc.y += v.y * msk[u];
                acc.z += v.z * msk[u]; acc.w += v.w * msk[u];
            }
        }
    }
    acc.x += __shfl_xor(acc.x, 32);
    acc.y += __shfl_xor(acc.y, 32);
    acc.z += __shfl_xor(acc.z, 32);
    acc.w += __shfl_xor(acc.w, 32);
    if (hi == 0) {
        const float inv = 1.f / (float)max(e1 - e0, 1);
        float4 o;
        o.x = acc.x * inv; o.y = acc.y * inv; o.z = acc.z * inv; o.w = acc.w * inv;
        *reinterpret_cast<float4*>(Xm + (size_t)n * (NREL * DIM) + r * DIM + 4 * hl) = o;
    }
}

// ---------------------------------------------------------------------------
// 4. Split-bf16 MFMA GEMM:  Out = act( [Hsrc | Xm] (Nx512) @ Wf (512x128) + b )
//    X@W ~= Xhi@Whi + Xlo@Whi + Xhi@Wlo  (exact split; dropped term ~2^-18).
//    mfma_f32_16x16x32_bf16; A row=lane&15, k=(lane>>4)*8+e; B col=lane&15;
//    D col=lane&15, row=(lane>>4)*4+reg (m89-verified). 4 waves/block, each
//    wave owns 32 rows (2 row-tiles); B-frags loaded dwordx4 from frag-ordered
//    global (L2-hot). No LDS, no barriers. In-place safe: a wave reads only
//    its own rows (kt<4) before storing them; clamped tail rows never stored.
// ---------------------------------------------------------------------------
template <bool RELU>
__global__ __launch_bounds__(256) void gemm_mfma(const float* __restrict__ Hsrc,
                                                 const float* __restrict__ Xm,
                                                 const ushort* __restrict__ Whi,
                                                 const ushort* __restrict__ Wlo,
                                                 const float* __restrict__ bias,
                                                 float* __restrict__ Out) {
    const int wave = threadIdx.x >> 6;
    const int lane = threadIdx.x & 63;
    const int r16 = lane & 15;
    const int kg  = lane >> 4;                       // 0..3
    const int wbase = blockIdx.x * 128 + wave * 32;  // wave's 32 rows

    f32x4 acc[2][8];
    #pragma unroll
    for (int t = 0; t < 2; ++t)
        #pragma unroll
        for (int ct = 0; ct < 8; ++ct) acc[t][ct] = (f32x4)0.0f;

    for (int kt = 0; kt < 16; ++kt) {
        const int kbase = kt * 32 + kg * 8;
        bf16x8 ahi[2], alo[2];
        #pragma unroll
        for (int t = 0; t < 2; ++t) {
            int row = wbase + t * 16 + r16;
            row = row < NNODES ? row : NNODES - 1;   // clamp; tail rows never stored
            const float* sp = (kt < 4)
                ? (Hsrc + (size_t)row * DIM + kbase)
                : (Xm + (size_t)row * (NREL * DIM) + (kbase - DIM));
            const float4 v0 = *reinterpret_cast<const float4*>(sp);
            const float4 v1 = *reinterpret_cast<const float4*>(sp + 4);
            const float xs[8] = {v0.x, v0.y, v0.z, v0.w, v1.x, v1.y, v1.z, v1.w};
            #pragma unroll
            for (int e = 0; e < 8; ++e) {
                const float x = xs[e];
                const ushort h = f2bf(x);
                ahi[t][e] = (short)h;
                alo[t][e] = (short)f2bf(x - bf2f(h));   // Sterbenz: subtraction exact
            }
        }
        const ushort* bp = Whi + (size_t)(kt * 8) * 512 + kg * 128 + r16 * 8;
        const ushort* bpl = Wlo + (size_t)(kt * 8) * 512 + kg * 128 + r16 * 8;
        #pragma unroll
        for (int ct = 0; ct < 8; ++ct) {
            const bf16x8 bhi = *reinterpret_cast<const bf16x8*>(bp + ct * 512);
            const bf16x8 blo = *reinterpret_cast<const bf16x8*>(bpl + ct * 512);
            #pragma unroll
            for (int t = 0; t < 2; ++t) {
                acc[t][ct] = __builtin_amdgcn_mfma_f32_16x16x32_bf16(ahi[t], bhi, acc[t][ct], 0, 0, 0);
                acc[t][ct] = __builtin_amdgcn_mfma_f32_16x16x32_bf16(alo[t], bhi, acc[t][ct], 0, 0, 0);
                acc[t][ct] = __builtin_amdgcn_mfma_f32_16x16x32_bf16(ahi[t], blo, acc[t][ct], 0, 0, 0);
            }
        }
    }
    // epilogue: bias + optional ReLU + store
    float bias_r[8];
    #pragma unroll
    for (int ct = 0; ct < 8; ++ct) bias_r[ct] = bias[ct * 16 + r16];
    #pragma unroll
    for (int t = 0; t < 2; ++t) {
        #pragma unroll
        for (int q = 0; q < 4; ++q) {
            const int row = wbase + t * 16 + kg * 4 + q;
            if (row >= NNODES) continue;
            #pragma unroll
            for (int ct = 0; ct < 8; ++ct) {
                float v = acc[t][ct][q] + bias_r[ct];
                if (RELU) v = fmaxf(v, 0.f);
                Out[(size_t)row * DIM + ct * 16 + r16] = v;
            }
        }
    }
}

// ---------------------------------------------------------------------------
extern "C" void kernel_launch(void* const* d_in, const int* in_sizes, int n_in,
                              void* d_out, int out_size, void* d_ws, size_t ws_size,
                              hipStream_t stream) {
    const float* feats  = (const float*)d_in[0];
    const int*   src    = (const int*)d_in[1];
    const int*   dst    = (const int*)d_in[2];
    const float* Wself  = (const float*)d_in[3];
    const float* bself  = (const float*)d_in[4];
    const float* Wneigh = (const float*)d_in[5];
    const float* Wm     = (const float*)d_in[6];
    const float* bmv    = (const float*)d_in[7];
    float* out = (float*)d_out;

    // workspace carve-up (4-byte words); H1 lives in d_out (in-place layer 1)
    float* ws   = (float*)d_ws;
    float* Wf   = ws;                        // 131072
    float* bias = Wf + 131072;               // 256
    int*   rptr = (int*)(bias + 256);        // 150016
    int*   degs = rptr + 150016;             // 150000
    int*   curs = degs + 150000;             // 150000
    int*   bsum = curs + 150000;             // 80
    int*   col  = bsum + 80;                 // 2400000
    ushort* Whi = (ushort*)(col + 2400000);  // 131072 u16 = 65536 words
    ushort* Wlo = Whi + 131072;              // 131072 u16 = 65536 words
    float* Xm   = (float*)(Wlo + 131072);    // 19200000
    float* H1   = out;
    // total ~= 89.2 MB

    hipMemsetAsync(degs, 0, (size_t)(150000 + 150000) * sizeof(int), stream);

    prep_weights<<<dim3(513, 2), 128, 0, stream>>>(Wself, bself, Wneigh, Wm, bmv, Wf, bias);
    wsplit<<<512, 256, 0, stream>>>(Wf, Whi, Wlo);

    deg_hist<<<dim3(NEDGE / 256, NREL), 256, 0, stream>>>(dst, degs);
    scan_local<<<dim3(NCHUNK, NREL), 256, 0, stream>>>(degs, rptr, bsum);
    scan_bsums<<<1, 64, 0, stream>>>(bsum);
    add_off<<<dim3(NCHUNK, NREL), 256, 0, stream>>>(bsum, rptr);
    fill_csr<<<dim3(NEDGE / 256, NREL), 256, 0, stream>>>(src, dst, rptr, curs, col);

    const int aggBlocks  = (NREL * NNODES) / 4;          // 4 waves/block, exact
    const int gemmBlocks = (NNODES + 127) / 128;         // 391

    // layer 0
    aggregate<<<aggBlocks, 256, 0, stream>>>(feats, rptr, col, Xm);
    gemm_mfma<true><<<gemmBlocks, 256, 0, stream>>>(feats, Xm, Whi, Wlo, bias, H1);

    // layer 1 (in place: Hsrc == Out == d_out)
    aggregate<<<aggBlocks, 256, 0, stream>>>(H1, rptr, col, Xm);
    gemm_mfma<false><<<gemmBlocks, 256, 0, stream>>>(H1, Xm, Whi + 65536, Wlo + 65536,
                                                     bias + 128, out);
}

// Round 8
// 634.213 us; speedup vs baseline: 1.3574x; 1.1302x over previous
//
#include <hip/hip_runtime.h>
#include <hip/hip_bf16.h>

#define NNODES 50000
#define DIM 128
#define NREL 3
#define NEDGE 800000
#define NCHUNK 25            // ceil(NNODES / 2048) scan chunks
// K of the fused GEMM = DIM (self) + NREL*DIM (means) = 512

typedef __attribute__((ext_vector_type(8))) short bf16x8;   // 8 bf16 in 4 VGPRs
typedef __attribute__((ext_vector_type(4))) float f32x4;    // MFMA accumulator

__device__ __forceinline__ ushort f2bf(float x) {           // RNE fp32->bf16
    unsigned u = __float_as_uint(x);
    return (ushort)((u + 0x7fffu + ((u >> 16) & 1u)) >> 16);
}
__device__ __forceinline__ float bf2f(ushort h) {
    return __uint_as_float(((unsigned)h) << 16);
}

// ---------------------------------------------------------------------------
// 1. Fold weights:  Wf[l] (512x128) = [ W_self@S ; W_neigh@Wm_0 ; W_neigh@Wm_1 ; W_neigh@Wm_2 ]
//    with S = sum_r Wm_r.   bias c[l] = b_self@S + bm.
//    (cat(embs)@Wm = Σ_r emb_r@Wm_r ; emb_r = h@W_self + b_self + mean_r@W_neigh)
// ---------------------------------------------------------------------------
__global__ void prep_weights(const float* __restrict__ Wself, const float* __restrict__ bself,
                             const float* __restrict__ Wneigh, const float* __restrict__ Wm,
                             const float* __restrict__ bm,
                             float* __restrict__ Wf, float* __restrict__ bias) {
    const int l = blockIdx.y;
    const int i = blockIdx.x;          // 0..512 (512 => bias row)
    const int j = threadIdx.x;         // 0..127
    const float* Wm_l = Wm + (size_t)l * 3 * DIM * DIM;
    if (i == 512) {
        float acc = bm[l * DIM + j];
        for (int k = 0; k < DIM; ++k) {
            float s = Wm_l[k * DIM + j] + Wm_l[(DIM + k) * DIM + j] + Wm_l[(2 * DIM + k) * DIM + j];
            acc += bself[l * DIM + k] * s;
        }
        bias[l * DIM + j] = acc;
        return;
    }
    float acc = 0.f;
    if (i < DIM) {                     // W_self @ S
        const float* A = Wself + (size_t)l * DIM * DIM + (size_t)i * DIM;
        for (int k = 0; k < DIM; ++k) {
            float s = Wm_l[k * DIM + j] + Wm_l[(DIM + k) * DIM + j] + Wm_l[(2 * DIM + k) * DIM + j];
            acc += A[k] * s;
        }
    } else {                           // W_neigh @ Wm_r  (row a of block r)
        const int r = (i - DIM) >> 7;
        const int a = (i - DIM) & 127;
        const float* A = Wneigh + (size_t)l * DIM * DIM + (size_t)a * DIM;
        const float* B = Wm_l + (size_t)r * DIM * DIM;
        for (int k = 0; k < DIM; ++k) acc += A[k] * B[k * DIM + j];
    }
    Wf[(size_t)l * 512 * DIM + (size_t)i * DIM + j] = acc;
}

// ---------------------------------------------------------------------------
// 1b. Split Wf into hi/lo bf16 in MFMA B-fragment order:
//     off = (((kt*8+ct)*4+kgrp)*16+col)*8 + e
// ---------------------------------------------------------------------------
__global__ void wsplit(const float* __restrict__ Wf, ushort* __restrict__ Whi,
                       ushort* __restrict__ Wlo) {
    const int idx = blockIdx.x * 256 + threadIdx.x;     // 2*512*128 = 131072
    if (idx >= 2 * 512 * DIM) return;
    const int l = idx >> 16;
    const int rem = idx & 65535;
    const int k = rem >> 7, j = rem & 127;
    const float w = Wf[idx];
    const ushort h = f2bf(w);
    const ushort lo = f2bf(w - bf2f(h));
    const int kt = k >> 5, kl = k & 31, kg = kl >> 3, e = kl & 7;
    const int ct = j >> 4, col = j & 15;
    const size_t off = (size_t)l * 65536 + ((((kt * 8 + ct) * 4 + kg) * 16 + col) * 8 + e);
    Whi[off] = h;
    Wlo[off] = lo;
}

// ---------------------------------------------------------------------------
// 1c. fp32 -> bf16 table conversion (coalesced; only needed for feats now)
// ---------------------------------------------------------------------------
__global__ __launch_bounds__(256) void h2bf(const float* __restrict__ in,
                                            ushort* __restrict__ out) {
    const int i = (blockIdx.x * 256 + threadIdx.x) * 4;   // NNODES*DIM/4 threads
    if (i >= NNODES * DIM) return;
    const float4 v = *reinterpret_cast<const float4*>(in + i);
    ushort4 o;
    o.x = f2bf(v.x); o.y = f2bf(v.y); o.z = f2bf(v.z); o.w = f2bf(v.w);
    *reinterpret_cast<ushort4*>(out + i) = o;
}

// ---------------------------------------------------------------------------
// 2. CSR build (per relation): degree histogram -> hierarchical scan -> fill
// ---------------------------------------------------------------------------
__global__ void deg_hist(const int* __restrict__ dst, int* __restrict__ degs) {
    const int e = blockIdx.x * 256 + threadIdx.x;
    const int r = blockIdx.y;
    if (e < NEDGE) atomicAdd(&degs[r * NNODES + dst[(size_t)r * NEDGE + e]], 1);
}

__global__ __launch_bounds__(256) void scan_local(const int* __restrict__ degs,
                                                  int* __restrict__ rptr,
                                                  int* __restrict__ bsum) {
    const int r = blockIdx.y;
    const int b = blockIdx.x;
    const int t = threadIdx.x;
    const int base = b * 2048;
    const int* d = degs + (size_t)r * NNODES;
    int v[8];
    int s = 0;
    #pragma unroll
    for (int i = 0; i < 8; ++i) {
        const int idx = base + t * 8 + i;
        v[i] = (idx < NNODES) ? d[idx] : 0;
        s += v[i];
        v[i] = s;
    }
    const int lane = t & 63;
    int wsc = s;
    #pragma unroll
    for (int off = 1; off < 64; off <<= 1) {
        int u = __shfl_up(wsc, off);
        if (lane >= off) wsc += u;
    }
    __shared__ int wtot[4];
    const int w = t >> 6;
    if (lane == 63) wtot[w] = wsc;
    __syncthreads();
    int wpre = 0;
    for (int i = 0; i < w; ++i) wpre += wtot[i];
    const int thrpre = wpre + wsc - s;
    int* p = rptr + (size_t)r * (NNODES + 1);
    #pragma unroll
    for (int i = 0; i < 8; ++i) {
        const int idx = base + t * 8 + i;
        if (idx < NNODES) p[idx + 1] = thrpre + v[i];
    }
    if (t == 255) bsum[r * NCHUNK + b] = wpre + wsc;
}

__global__ void scan_bsums(int* __restrict__ bsum) {
    const int r = threadIdx.x;
    if (r >= NREL) return;
    int acc = 0;
    for (int b = 0; b < NCHUNK; ++b) {
        const int t = bsum[r * NCHUNK + b];
        bsum[r * NCHUNK + b] = acc;
        acc += t;
    }
}

__global__ __launch_bounds__(256) void add_off(const int* __restrict__ bsum,
                                               int* __restrict__ rptr) {
    const int r = blockIdx.y;
    const int b = blockIdx.x;
    const int off = bsum[r * NCHUNK + b];
    int* p = rptr + (size_t)r * (NNODES + 1);
    if (b == 0 && threadIdx.x == 0) p[0] = 0;
    #pragma unroll
    for (int i = 0; i < 8; ++i) {
        const int idx = b * 2048 + threadIdx.x * 8 + i;
        if (idx < NNODES) p[idx + 1] += off;
    }
}

__global__ void fill_csr(const int* __restrict__ src, const int* __restrict__ dst,
                         const int* __restrict__ rptr, int* __restrict__ cursor,
                         int* __restrict__ col) {
    const int e = blockIdx.x * 256 + threadIdx.x;
    const int r = blockIdx.y;
    if (e >= NEDGE) return;
    const int d = dst[(size_t)r * NEDGE + e];
    const int pos = rptr[(size_t)r * (NNODES + 1) + d] + atomicAdd(&cursor[r * NNODES + d], 1);
    col[(size_t)r * NEDGE + pos] = src[(size_t)r * NEDGE + e];
}

// ---------------------------------------------------------------------------
// 3. Pull aggregation over the bf16 table: one wave per (node, relation).
//    Half-wave per edge-row (32 x ushort4 = 256B). Unroll 16 => 8 independent
//    8B loads in flight per half-wave; fp32 accumulate; bf16 mean out.
// ---------------------------------------------------------------------------
__global__ __launch_bounds__(256) void aggregate(const ushort* __restrict__ H,
                                                 const int* __restrict__ rptr,
                                                 const int* __restrict__ col,
                                                 ushort* __restrict__ Xm) {
    const int wid = (blockIdx.x * 256 + threadIdx.x) >> 6;
    const int lane = threadIdx.x & 63;
    if (wid >= NREL * NNODES) return;
    const int r = wid / NNODES;
    const int n = wid - r * NNODES;
    const int e0 = rptr[(size_t)r * (NNODES + 1) + n];
    const int e1 = rptr[(size_t)r * (NNODES + 1) + n + 1];
    const int* cl = col + (size_t)r * NEDGE;
    const int hi = lane >> 5;
    const int hl = lane & 31;
    float4 acc = make_float4(0.f, 0.f, 0.f, 0.f);
    for (int e = e0; e < e1; e += 64) {
        const int ce = (e + lane < e1) ? cl[e + lane] : 0;
        const int cnt = min(64, e1 - e);
        for (int j = 0; j < cnt; j += 16) {
            int   sidx[8];
            float msk[8];
            #pragma unroll
            for (int u = 0; u < 8; ++u) {
                const int eid = j + 2 * u + hi;          // <= 63 by construction
                sidx[u] = __shfl(ce, eid);
                msk[u] = (eid < cnt) ? 1.f : 0.f;
            }
            #pragma unroll
            for (int u = 0; u < 8; ++u) {
                const ushort4 v = *reinterpret_cast<const ushort4*>(
                    H + (size_t)sidx[u] * DIM + 4 * hl);
                acc.x += bf2f(v.x) * msk[u]; acc.y += bf2f(v.y) * msk[u];
                acc.z += bf2f(v.z) * msk[u]; acc.w += bf2f(v.w) * msk[u];
            }
        }
    }
    acc.x += __shfl_xor(acc.x, 32);
    acc.y += __shfl_xor(acc.y, 32);
    acc.z += __shfl_xor(acc.z, 32);
    acc.w += __shfl_xor(acc.w, 32);
    if (hi == 0) {
        const float inv = 1.f / (float)max(e1 - e0, 1);
        ushort4 o;
        o.x = f2bf(acc.x * inv); o.y = f2bf(acc.y * inv);
        o.z = f2bf(acc.z * inv); o.w = f2bf(acc.w * inv);
        *reinterpret_cast<ushort4*>(Xm + (size_t)n * (NREL * DIM) + r * DIM + 4 * hl) = o;
    }
}

// ---------------------------------------------------------------------------
// 4. Split-bf16 MFMA GEMM:  Out = act( [Hsrc | Xm] (Nx512) @ Wf (512x128) + b )
//    Self cols (kt<4, fp32 src):  Xhi@Whi + Xlo@Whi + Xhi@Wlo   (3 MFMAs)
//    Mean cols (kt>=4, bf16 src): X@Whi + X@Wlo                 (2 MFMAs)
//    mfma_f32_16x16x32_bf16; A row=lane&15, k=(lane>>4)*8+e; B col=lane&15;
//    D col=lane&15, row=(lane>>4)*4+reg (m89-verified). 4 waves/block, each
//    wave owns 32 rows; B-frags via dwordx4 from frag-ordered global (L2-hot).
//    No LDS, no barriers. In-place safe: a wave reads only its own rows
//    (kt<4) before storing them; clamped tail rows never stored.
//    WRITEBF: also emit bf16 copy of Out into OutBf (fuses next layer's h2bf).
// ---------------------------------------------------------------------------
template <bool RELU, bool WRITEBF>
__global__ __launch_bounds__(256) void gemm_mfma(const float* __restrict__ Hsrc,
                                                 const ushort* __restrict__ Xm,
                                                 const ushort* __restrict__ Whi,
                                                 const ushort* __restrict__ Wlo,
                                                 const float* __restrict__ bias,
                                                 float* __restrict__ Out,
                                                 ushort* __restrict__ OutBf) {
    const int wave = threadIdx.x >> 6;
    const int lane = threadIdx.x & 63;
    const int r16 = lane & 15;
    const int kg  = lane >> 4;                       // 0..3
    const int wbase = blockIdx.x * 128 + wave * 32;  // wave's 32 rows

    f32x4 acc[2][8];
    #pragma unroll
    for (int t = 0; t < 2; ++t)
        #pragma unroll
        for (int ct = 0; ct < 8; ++ct) acc[t][ct] = (f32x4)0.0f;

    int rowc[2];
    #pragma unroll
    for (int t = 0; t < 2; ++t) {
        int row = wbase + t * 16 + r16;
        rowc[t] = row < NNODES ? row : NNODES - 1;   // clamp; tail rows never stored
    }

    // ---- kt 0..3: self columns from fp32 Hsrc, hi/lo split (3 MFMAs)
    for (int kt = 0; kt < 4; ++kt) {
        const int kbase = kt * 32 + kg * 8;
        bf16x8 ahi[2], alo[2];
        #pragma unroll
        for (int t = 0; t < 2; ++t) {
            const float* sp = Hsrc + (size_t)rowc[t] * DIM + kbase;
            const float4 v0 = *reinterpret_cast<const float4*>(sp);
            const float4 v1 = *reinterpret_cast<const float4*>(sp + 4);
            const float xs[8] = {v0.x, v0.y, v0.z, v0.w, v1.x, v1.y, v1.z, v1.w};
            #pragma unroll
            for (int e = 0; e < 8; ++e) {
                const float x = xs[e];
                const ushort h = f2bf(x);
                ahi[t][e] = (short)h;
                alo[t][e] = (short)f2bf(x - bf2f(h));   // Sterbenz: subtraction exact
            }
        }
        const ushort* bp  = Whi + (size_t)(kt * 8) * 512 + kg * 128 + r16 * 8;
        const ushort* bpl = Wlo + (size_t)(kt * 8) * 512 + kg * 128 + r16 * 8;
        #pragma unroll
        for (int ct = 0; ct < 8; ++ct) {
            const bf16x8 bhi = *reinterpret_cast<const bf16x8*>(bp + ct * 512);
            const bf16x8 blo = *reinterpret_cast<const bf16x8*>(bpl + ct * 512);
            #pragma unroll
            for (int t = 0; t < 2; ++t) {
                acc[t][ct] = __builtin_amdgcn_mfma_f32_16x16x32_bf16(ahi[t], bhi, acc[t][ct], 0, 0, 0);
                acc[t][ct] = __builtin_amdgcn_mfma_f32_16x16x32_bf16(alo[t], bhi, acc[t][ct], 0, 0, 0);
                acc[t][ct] = __builtin_amdgcn_mfma_f32_16x16x32_bf16(ahi[t], blo, acc[t][ct], 0, 0, 0);
            }
        }
    }
    // ---- kt 4..15: mean columns from bf16 Xm, direct A-frag load (2 MFMAs)
    for (int kt = 4; kt < 16; ++kt) {
        const int kbase = kt * 32 + kg * 8 - DIM;    // offset within Xm row
        bf16x8 a[2];
        #pragma unroll
        for (int t = 0; t < 2; ++t)
            a[t] = *reinterpret_cast<const bf16x8*>(Xm + (size_t)rowc[t] * (NREL * DIM) + kbase);
        const ushort* bp  = Whi + (size_t)(kt * 8) * 512 + kg * 128 + r16 * 8;
        const ushort* bpl = Wlo + (size_t)(kt * 8) * 512 + kg * 128 + r16 * 8;
        #pragma unroll
        for (int ct = 0; ct < 8; ++ct) {
            const bf16x8 bhi = *reinterpret_cast<const bf16x8*>(bp + ct * 512);
            const bf16x8 blo = *reinterpret_cast<const bf16x8*>(bpl + ct * 512);
            #pragma unroll
            for (int t = 0; t < 2; ++t) {
                acc[t][ct] = __builtin_amdgcn_mfma_f32_16x16x32_bf16(a[t], bhi, acc[t][ct], 0, 0, 0);
                acc[t][ct] = __builtin_amdgcn_mfma_f32_16x16x32_bf16(a[t], blo, acc[t][ct], 0, 0, 0);
            }
        }
    }
    // epilogue: bias + optional ReLU + store (fp32, and bf16 copy if WRITEBF)
    float bias_r[8];
    #pragma unroll
    for (int ct = 0; ct < 8; ++ct) bias_r[ct] = bias[ct * 16 + r16];
    #pragma unroll
    for (int t = 0; t < 2; ++t) {
        #pragma unroll
        for (int q = 0; q < 4; ++q) {
            const int row = wbase + t * 16 + kg * 4 + q;
            if (row >= NNODES) continue;
            #pragma unroll
            for (int ct = 0; ct < 8; ++ct) {
                float v = acc[t][ct][q] + bias_r[ct];
                if (RELU) v = fmaxf(v, 0.f);
                Out[(size_t)row * DIM + ct * 16 + r16] = v;
                if (WRITEBF) OutBf[(size_t)row * DIM + ct * 16 + r16] = f2bf(v);
            }
        }
    }
}

// ---------------------------------------------------------------------------
extern "C" void kernel_launch(void* const* d_in, const int* in_sizes, int n_in,
                              void* d_out, int out_size, void* d_ws, size_t ws_size,
                              hipStream_t stream) {
    const float* feats  = (const float*)d_in[0];
    const int*   src    = (const int*)d_in[1];
    const int*   dst    = (const int*)d_in[2];
    const float* Wself  = (const float*)d_in[3];
    const float* bself  = (const float*)d_in[4];
    const float* Wneigh = (const float*)d_in[5];
    const float* Wm     = (const float*)d_in[6];
    const float* bmv    = (const float*)d_in[7];
    float* out = (float*)d_out;

    // workspace carve-up (4-byte words); H1 lives in d_out (in-place layer 1)
    float* ws   = (float*)d_ws;
    float* Wf   = ws;                        // 131072
    float* bias = Wf + 131072;               // 256
    int*   rptr = (int*)(bias + 256);        // 150016
    int*   degs = rptr + 150016;             // 150000
    int*   curs = degs + 150000;             // 150000
    int*   bsum = curs + 150000;             // 80
    int*   col  = bsum + 80;                 // 2400000
    ushort* Whi = (ushort*)(col + 2400000);  // 131072 u16 = 65536 words
    ushort* Wlo = Whi + 131072;              // 131072 u16 = 65536 words
    ushort* Fbf = Wlo + 131072;              // N*128 u16  = 3200000 words
    ushort* Xm  = Fbf + 6400000;             // N*384 u16  = 9600000 words
    float* H1   = out;
    // total ~= 63.6 MB

    hipMemsetAsync(degs, 0, (size_t)(150000 + 150000) * sizeof(int), stream);

    prep_weights<<<dim3(513, 2), 128, 0, stream>>>(Wself, bself, Wneigh, Wm, bmv, Wf, bias);
    wsplit<<<512, 256, 0, stream>>>(Wf, Whi, Wlo);

    deg_hist<<<dim3(NEDGE / 256, NREL), 256, 0, stream>>>(dst, degs);
    scan_local<<<dim3(NCHUNK, NREL), 256, 0, stream>>>(degs, rptr, bsum);
    scan_bsums<<<1, 64, 0, stream>>>(bsum);
    add_off<<<dim3(NCHUNK, NREL), 256, 0, stream>>>(bsum, rptr);
    fill_csr<<<dim3(NEDGE / 256, NREL), 256, 0, stream>>>(src, dst, rptr, curs, col);

    const int aggBlocks  = (NREL * NNODES) / 4;          // 4 waves/block, exact
    const int gemmBlocks = (NNODES + 127) / 128;         // 391
    const int cvtBlocks  = (NNODES * DIM) / 4 / 256;     // 6250, exact

    // layer 0  (GEMM also emits bf16 H1 -> Fbf, fusing layer-1's h2bf)
    h2bf<<<cvtBlocks, 256, 0, stream>>>(feats, Fbf);
    aggregate<<<aggBlocks, 256, 0, stream>>>(Fbf, rptr, col, Xm);
    gemm_mfma<true, true><<<gemmBlocks, 256, 0, stream>>>(feats, Xm, Whi, Wlo, bias, H1, Fbf);

    // layer 1 (in place: Hsrc == Out == d_out)
    aggregate<<<aggBlocks, 256, 0, stream>>>(Fbf, rptr, col, Xm);
    gemm_mfma<false, false><<<gemmBlocks, 256, 0, stream>>>(H1, Xm, Whi + 65536, Wlo + 65536,
                                                            bias + 128, out, Fbf);
}

// Round 9
// 577.178 us; speedup vs baseline: 1.4916x; 1.0988x over previous
//
#include <hip/hip_runtime.h>
#include <hip/hip_bf16.h>

#define NNODES 50000
#define DIM 128
#define NREL 3
#define NEDGE 800000
#define CAP 64               // slot capacity per (rel,node); P(deg>64)~0 (mean 16, sigma 4)
// K of the fused GEMM = DIM (self) + NREL*DIM (means) = 512

typedef __attribute__((ext_vector_type(8))) short bf16x8;   // 8 bf16 in 4 VGPRs
typedef __attribute__((ext_vector_type(4))) float f32x4;    // MFMA accumulator

__device__ __forceinline__ ushort f2bf(float x) {           // RNE fp32->bf16
    unsigned u = __float_as_uint(x);
    return (ushort)((u + 0x7fffu + ((u >> 16) & 1u)) >> 16);
}
__device__ __forceinline__ float bf2f(ushort h) {
    return __uint_as_float(((unsigned)h) << 16);
}

// ---------------------------------------------------------------------------
// 1. Fold weights:  Wf[l] (512x128) = [ W_self@S ; W_neigh@Wm_0 ; W_neigh@Wm_1 ; W_neigh@Wm_2 ]
//    with S = sum_r Wm_r.   bias c[l] = b_self@S + bm.
//    (cat(embs)@Wm = Σ_r emb_r@Wm_r ; emb_r = h@W_self + b_self + mean_r@W_neigh)
// ---------------------------------------------------------------------------
__global__ void prep_weights(const float* __restrict__ Wself, const float* __restrict__ bself,
                             const float* __restrict__ Wneigh, const float* __restrict__ Wm,
                             const float* __restrict__ bm,
                             float* __restrict__ Wf, float* __restrict__ bias) {
    const int l = blockIdx.y;
    const int i = blockIdx.x;          // 0..512 (512 => bias row)
    const int j = threadIdx.x;         // 0..127
    const float* Wm_l = Wm + (size_t)l * 3 * DIM * DIM;
    if (i == 512) {
        float acc = bm[l * DIM + j];
        for (int k = 0; k < DIM; ++k) {
            float s = Wm_l[k * DIM + j] + Wm_l[(DIM + k) * DIM + j] + Wm_l[(2 * DIM + k) * DIM + j];
            acc += bself[l * DIM + k] * s;
        }
        bias[l * DIM + j] = acc;
        return;
    }
    float acc = 0.f;
    if (i < DIM) {                     // W_self @ S
        const float* A = Wself + (size_t)l * DIM * DIM + (size_t)i * DIM;
        for (int k = 0; k < DIM; ++k) {
            float s = Wm_l[k * DIM + j] + Wm_l[(DIM + k) * DIM + j] + Wm_l[(2 * DIM + k) * DIM + j];
            acc += A[k] * s;
        }
    } else {                           // W_neigh @ Wm_r  (row a of block r)
        const int r = (i - DIM) >> 7;
        const int a = (i - DIM) & 127;
        const float* A = Wneigh + (size_t)l * DIM * DIM + (size_t)a * DIM;
        const float* B = Wm_l + (size_t)r * DIM * DIM;
        for (int k = 0; k < DIM; ++k) acc += A[k] * B[k * DIM + j];
    }
    Wf[(size_t)l * 512 * DIM + (size_t)i * DIM + j] = acc;
}

// ---------------------------------------------------------------------------
// 1b. Split Wf into hi/lo bf16 in MFMA B-fragment order:
//     off = (((kt*8+ct)*4+kgrp)*16+col)*8 + e
// ---------------------------------------------------------------------------
__global__ void wsplit(const float* __restrict__ Wf, ushort* __restrict__ Whi,
                       ushort* __restrict__ Wlo) {
    const int idx = blockIdx.x * 256 + threadIdx.x;     // 2*512*128 = 131072
    if (idx >= 2 * 512 * DIM) return;
    const int l = idx >> 16;
    const int rem = idx & 65535;
    const int k = rem >> 7, j = rem & 127;
    const float w = Wf[idx];
    const ushort h = f2bf(w);
    const ushort lo = f2bf(w - bf2f(h));
    const int kt = k >> 5, kl = k & 31, kg = kl >> 3, e = kl & 7;
    const int ct = j >> 4, col = j & 15;
    const size_t off = (size_t)l * 65536 + ((((kt * 8 + ct) * 4 + kg) * 16 + col) * 8 + e);
    Whi[off] = h;
    Wlo[off] = lo;
}

// ---------------------------------------------------------------------------
// 1c. fp32 -> bf16 table conversion (coalesced; only needed for feats)
// ---------------------------------------------------------------------------
__global__ __launch_bounds__(256) void h2bf(const float* __restrict__ in,
                                            ushort* __restrict__ out) {
    const int i = (blockIdx.x * 256 + threadIdx.x) * 4;   // NNODES*DIM/4 threads
    if (i >= NNODES * DIM) return;
    const float4 v = *reinterpret_cast<const float4*>(in + i);
    ushort4 o;
    o.x = f2bf(v.x); o.y = f2bf(v.y); o.z = f2bf(v.z); o.w = f2bf(v.w);
    *reinterpret_cast<ushort4*>(out + i) = o;
}

// ---------------------------------------------------------------------------
// 2. Slot-append adjacency build (replaces deg_hist+scan+fill_csr):
//    edge order within a node is irrelevant for a mean, so append into
//    fixed-capacity slots; degree comes from the cursor. 4 independent
//    edge-chains per thread for latency hiding.
// ---------------------------------------------------------------------------
__global__ __launch_bounds__(256) void fill_slots(const int* __restrict__ src,
                                                  const int* __restrict__ dst,
                                                  int* __restrict__ curs,
                                                  int* __restrict__ slot) {
    const int r = blockIdx.y;
    const int e0 = blockIdx.x * 1024 + threadIdx.x;
    #pragma unroll
    for (int u = 0; u < 4; ++u) {
        const int e = e0 + u * 256;
        if (e < NEDGE) {
            const int d = dst[(size_t)r * NEDGE + e];
            const int pos = atomicAdd(&curs[r * NNODES + d], 1);
            if (pos < CAP)
                slot[((size_t)r * NNODES + d) * CAP + pos] = src[(size_t)r * NEDGE + e];
        }
    }
}

// ---------------------------------------------------------------------------
// 3. Pull aggregation over the bf16 table: one wave per (node, relation).
//    deg <= CAP = 64, so one slot-load covers all edges. Half-wave per
//    edge-row (32 x ushort4 = 256B); unroll => 8 independent 8B loads in
//    flight per half-wave; fp32 accumulate; bf16 mean out.
// ---------------------------------------------------------------------------
__global__ __launch_bounds__(256) void aggregate(const ushort* __restrict__ H,
                                                 const int* __restrict__ curs,
                                                 const int* __restrict__ slot,
                                                 ushort* __restrict__ Xm) {
    const int wid = (blockIdx.x * 256 + threadIdx.x) >> 6;
    const int lane = threadIdx.x & 63;
    if (wid >= NREL * NNODES) return;
    const int r = wid / NNODES;
    const int n = wid - r * NNODES;
    const int deg = min(curs[wid], CAP);
    const int* cl = slot + (size_t)wid * CAP;
    const int hi = lane >> 5;
    const int hl = lane & 31;
    float4 acc = make_float4(0.f, 0.f, 0.f, 0.f);
    const int ce = (lane < deg) ? cl[lane] : 0;
    for (int j = 0; j < deg; j += 16) {
        int   sidx[8];
        float msk[8];
        #pragma unroll
        for (int u = 0; u < 8; ++u) {
            const int eid = j + 2 * u + hi;              // <= 63 by construction
            sidx[u] = __shfl(ce, eid);
            msk[u] = (eid < deg) ? 1.f : 0.f;
        }
        #pragma unroll
        for (int u = 0; u < 8; ++u) {
            const ushort4 v = *reinterpret_cast<const ushort4*>(
                H + (size_t)sidx[u] * DIM + 4 * hl);
            acc.x += bf2f(v.x) * msk[u]; acc.y += bf2f(v.y) * msk[u];
            acc.z += bf2f(v.z) * msk[u]; acc.w += bf2f(v.w) * msk[u];
        }
    }
    acc.x += __shfl_xor(acc.x, 32);
    acc.y += __shfl_xor(acc.y, 32);
    acc.z += __shfl_xor(acc.z, 32);
    acc.w += __shfl_xor(acc.w, 32);
    if (hi == 0) {
        const float inv = 1.f / (float)max(deg, 1);
        ushort4 o;
        o.x = f2bf(acc.x * inv); o.y = f2bf(acc.y * inv);
        o.z = f2bf(acc.z * inv); o.w = f2bf(acc.w * inv);
        *reinterpret_cast<ushort4*>(Xm + (size_t)n * (NREL * DIM) + r * DIM + 4 * hl) = o;
    }
}

// ---------------------------------------------------------------------------
// 4. Split-bf16 MFMA GEMM:  Out = act( [Hsrc | Xm] (Nx512) @ Wf (512x128) + b )
//    Self cols (kt<4, fp32 src):  Xhi@Whi + Xlo@Whi + Xhi@Wlo   (3 MFMAs)
//    Mean cols (kt>=4, bf16 src): X@Whi + X@Wlo                 (2 MFMAs)
//    mfma_f32_16x16x32_bf16; A row=lane&15, k=(lane>>4)*8+e; B col=lane&15;
//    D col=lane&15, row=(lane>>4)*4+reg (m89-verified). 4 waves/block, each
//    wave owns 32 rows; B-frags via dwordx4 from frag-ordered global (L2-hot).
//    No LDS, no barriers. In-place safe. WRITEBF fuses next layer's h2bf.
// ---------------------------------------------------------------------------
template <bool RELU, bool WRITEBF>
__global__ __launch_bounds__(256) void gemm_mfma(const float* __restrict__ Hsrc,
                                                 const ushort* __restrict__ Xm,
                                                 const ushort* __restrict__ Whi,
                                                 const ushort* __restrict__ Wlo,
                                                 const float* __restrict__ bias,
                                                 float* __restrict__ Out,
                                                 ushort* __restrict__ OutBf) {
    const int wave = threadIdx.x >> 6;
    const int lane = threadIdx.x & 63;
    const int r16 = lane & 15;
    const int kg  = lane >> 4;                       // 0..3
    const int wbase = blockIdx.x * 128 + wave * 32;  // wave's 32 rows

    f32x4 acc[2][8];
    #pragma unroll
    for (int t = 0; t < 2; ++t)
        #pragma unroll
        for (int ct = 0; ct < 8; ++ct) acc[t][ct] = (f32x4)0.0f;

    int rowc[2];
    #pragma unroll
    for (int t = 0; t < 2; ++t) {
        int row = wbase + t * 16 + r16;
        rowc[t] = row < NNODES ? row : NNODES - 1;   // clamp; tail rows never stored
    }

    // ---- kt 0..3: self columns from fp32 Hsrc, hi/lo split (3 MFMAs)
    for (int kt = 0; kt < 4; ++kt) {
        const int kbase = kt * 32 + kg * 8;
        bf16x8 ahi[2], alo[2];
        #pragma unroll
        for (int t = 0; t < 2; ++t) {
            const float* sp = Hsrc + (size_t)rowc[t] * DIM + kbase;
            const float4 v0 = *reinterpret_cast<const float4*>(sp);
            const float4 v1 = *reinterpret_cast<const float4*>(sp + 4);
            const float xs[8] = {v0.x, v0.y, v0.z, v0.w, v1.x, v1.y, v1.z, v1.w};
            #pragma unroll
            for (int e = 0; e < 8; ++e) {
                const float x = xs[e];
                const ushort h = f2bf(x);
                ahi[t][e] = (short)h;
                alo[t][e] = (short)f2bf(x - bf2f(h));   // Sterbenz: subtraction exact
            }
        }
        const ushort* bp  = Whi + (size_t)(kt * 8) * 512 + kg * 128 + r16 * 8;
        const ushort* bpl = Wlo + (size_t)(kt * 8) * 512 + kg * 128 + r16 * 8;
        #pragma unroll
        for (int ct = 0; ct < 8; ++ct) {
            const bf16x8 bhi = *reinterpret_cast<const bf16x8*>(bp + ct * 512);
            const bf16x8 blo = *reinterpret_cast<const bf16x8*>(bpl + ct * 512);
            #pragma unroll
            for (int t = 0; t < 2; ++t) {
                acc[t][ct] = __builtin_amdgcn_mfma_f32_16x16x32_bf16(ahi[t], bhi, acc[t][ct], 0, 0, 0);
                acc[t][ct] = __builtin_amdgcn_mfma_f32_16x16x32_bf16(alo[t], bhi, acc[t][ct], 0, 0, 0);
                acc[t][ct] = __builtin_amdgcn_mfma_f32_16x16x32_bf16(ahi[t], blo, acc[t][ct], 0, 0, 0);
            }
        }
    }
    // ---- kt 4..15: mean columns from bf16 Xm, direct A-frag load (2 MFMAs)
    for (int kt = 4; kt < 16; ++kt) {
        const int kbase = kt * 32 + kg * 8 - DIM;    // offset within Xm row
        bf16x8 a[2];
        #pragma unroll
        for (int t = 0; t < 2; ++t)
            a[t] = *reinterpret_cast<const bf16x8*>(Xm + (size_t)rowc[t] * (NREL * DIM) + kbase);
        const ushort* bp  = Whi + (size_t)(kt * 8) * 512 + kg * 128 + r16 * 8;
        const ushort* bpl = Wlo + (size_t)(kt * 8) * 512 + kg * 128 + r16 * 8;
        #pragma unroll
        for (int ct = 0; ct < 8; ++ct) {
            const bf16x8 bhi = *reinterpret_cast<const bf16x8*>(bp + ct * 512);
            const bf16x8 blo = *reinterpret_cast<const bf16x8*>(bpl + ct * 512);
            #pragma unroll
            for (int t = 0; t < 2; ++t) {
                acc[t][ct] = __builtin_amdgcn_mfma_f32_16x16x32_bf16(a[t], bhi, acc[t][ct], 0, 0, 0);
                acc[t][ct] = __builtin_amdgcn_mfma_f32_16x16x32_bf16(a[t], blo, acc[t][ct], 0, 0, 0);
            }
        }
    }
    // epilogue: bias + optional ReLU + store (fp32, and bf16 copy if WRITEBF)
    float bias_r[8];
    #pragma unroll
    for (int ct = 0; ct < 8; ++ct) bias_r[ct] = bias[ct * 16 + r16];
    #pragma unroll
    for (int t = 0; t < 2; ++t) {
        #pragma unroll
        for (int q = 0; q < 4; ++q) {
            const int row = wbase + t * 16 + kg * 4 + q;
            if (row >= NNODES) continue;
            #pragma unroll
            for (int ct = 0; ct < 8; ++ct) {
                float v = acc[t][ct][q] + bias_r[ct];
                if (RELU) v = fmaxf(v, 0.f);
                Out[(size_t)row * DIM + ct * 16 + r16] = v;
                if (WRITEBF) OutBf[(size_t)row * DIM + ct * 16 + r16] = f2bf(v);
            }
        }
    }
}

// ---------------------------------------------------------------------------
extern "C" void kernel_launch(void* const* d_in, const int* in_sizes, int n_in,
                              void* d_out, int out_size, void* d_ws, size_t ws_size,
                              hipStream_t stream) {
    const float* feats  = (const float*)d_in[0];
    const int*   src    = (const int*)d_in[1];
    const int*   dst    = (const int*)d_in[2];
    const float* Wself  = (const float*)d_in[3];
    const float* bself  = (const float*)d_in[4];
    const float* Wneigh = (const float*)d_in[5];
    const float* Wm     = (const float*)d_in[6];
    const float* bmv    = (const float*)d_in[7];
    float* out = (float*)d_out;

    // workspace carve-up (4-byte words); H1 lives in d_out (in-place layer 1)
    float* ws   = (float*)d_ws;
    float* Wf   = ws;                        // 131072
    float* bias = Wf + 131072;               // 256
    int*   curs = (int*)(bias + 256);        // 3*N               = 150000
    int*   slot = curs + 150000;             // 3*N*CAP           = 9600000
    ushort* Whi = (ushort*)(slot + 9600000); // 131072 u16 = 65536 words
    ushort* Wlo = Whi + 131072;              // 131072 u16 = 65536 words
    ushort* Fbf = Wlo + 131072;              // N*128 u16  = 3200000 words
    ushort* Xm  = Fbf + 6400000;             // N*384 u16  = 9600000 words
    float* H1   = out;
    // total ~= 91.2 MB (<= 114 MB proven in round 4)

    hipMemsetAsync(curs, 0, (size_t)150000 * sizeof(int), stream);

    prep_weights<<<dim3(513, 2), 128, 0, stream>>>(Wself, bself, Wneigh, Wm, bmv, Wf, bias);
    wsplit<<<512, 256, 0, stream>>>(Wf, Whi, Wlo);

    // adjacency slots (built once, used by both layers)
    fill_slots<<<dim3((NEDGE + 1023) / 1024, NREL), 256, 0, stream>>>(src, dst, curs, slot);

    const int aggBlocks  = (NREL * NNODES) / 4;          // 4 waves/block, exact
    const int gemmBlocks = (NNODES + 127) / 128;         // 391
    const int cvtBlocks  = (NNODES * DIM) / 4 / 256;     // 6250, exact

    // layer 0  (GEMM also emits bf16 H1 -> Fbf, fusing layer-1's h2bf)
    h2bf<<<cvtBlocks, 256, 0, stream>>>(feats, Fbf);
    aggregate<<<aggBlocks, 256, 0, stream>>>(Fbf, curs, slot, Xm);
    gemm_mfma<true, true><<<gemmBlocks, 256, 0, stream>>>(feats, Xm, Whi, Wlo, bias, H1, Fbf);

    // layer 1 (in place: Hsrc == Out == d_out)
    aggregate<<<aggBlocks, 256, 0, stream>>>(Fbf, curs, slot, Xm);
    gemm_mfma<false, false><<<gemmBlocks, 256, 0, stream>>>(H1, Xm, Whi + 65536, Wlo + 65536,
                                                            bias + 128, out, Fbf);
}

// Round 10
// 406.568 us; speedup vs baseline: 2.1175x; 1.4196x over previous
//
#include <hip/hip_runtime.h>
#include <hip/hip_bf16.h>

#define NNODES 50000
#define DIM 128
#define NREL 3
#define NEDGE 800000
#define NBKT 196             // ceil(NNODES/256) coarse buckets (dst>>8)
#define CH 391               // ceil(NEDGE/2048) edge chunks
// K of the fused GEMM = DIM (self) + NREL*DIM (means) = 512

typedef __attribute__((ext_vector_type(8))) short bf16x8;   // 8 bf16 in 4 VGPRs
typedef __attribute__((ext_vector_type(4))) float f32x4;    // MFMA accumulator

__device__ __forceinline__ ushort f2bf(float x) {           // RNE fp32->bf16
    unsigned u = __float_as_uint(x);
    return (ushort)((u + 0x7fffu + ((u >> 16) & 1u)) >> 16);
}
__device__ __forceinline__ float bf2f(ushort h) {
    return __uint_as_float(((unsigned)h) << 16);
}

// ---------------------------------------------------------------------------
// 1. Fold weights:  Wf[l] (512x128) = [ W_self@S ; W_neigh@Wm_0 ; W_neigh@Wm_1 ; W_neigh@Wm_2 ]
//    with S = sum_r Wm_r.   bias c[l] = b_self@S + bm.
//    (cat(embs)@Wm = Σ_r emb_r@Wm_r ; emb_r = h@W_self + b_self + mean_r@W_neigh)
// ---------------------------------------------------------------------------
__global__ void prep_weights(const float* __restrict__ Wself, const float* __restrict__ bself,
                             const float* __restrict__ Wneigh, const float* __restrict__ Wm,
                             const float* __restrict__ bm,
                             float* __restrict__ Wf, float* __restrict__ bias) {
    const int l = blockIdx.y;
    const int i = blockIdx.x;          // 0..512 (512 => bias row)
    const int j = threadIdx.x;         // 0..127
    const float* Wm_l = Wm + (size_t)l * 3 * DIM * DIM;
    if (i == 512) {
        float acc = bm[l * DIM + j];
        for (int k = 0; k < DIM; ++k) {
            float s = Wm_l[k * DIM + j] + Wm_l[(DIM + k) * DIM + j] + Wm_l[(2 * DIM + k) * DIM + j];
            acc += bself[l * DIM + k] * s;
        }
        bias[l * DIM + j] = acc;
        return;
    }
    float acc = 0.f;
    if (i < DIM) {                     // W_self @ S
        const float* A = Wself + (size_t)l * DIM * DIM + (size_t)i * DIM;
        for (int k = 0; k < DIM; ++k) {
            float s = Wm_l[k * DIM + j] + Wm_l[(DIM + k) * DIM + j] + Wm_l[(2 * DIM + k) * DIM + j];
            acc += A[k] * s;
        }
    } else {                           // W_neigh @ Wm_r  (row a of block r)
        const int r = (i - DIM) >> 7;
        const int a = (i - DIM) & 127;
        const float* A = Wneigh + (size_t)l * DIM * DIM + (size_t)a * DIM;
        const float* B = Wm_l + (size_t)r * DIM * DIM;
        for (int k = 0; k < DIM; ++k) acc += A[k] * B[k * DIM + j];
    }
    Wf[(size_t)l * 512 * DIM + (size_t)i * DIM + j] = acc;
}

// ---------------------------------------------------------------------------
// 1b. Split Wf into hi/lo bf16 in MFMA B-fragment order:
//     off = (((kt*8+ct)*4+kgrp)*16+col)*8 + e
// ---------------------------------------------------------------------------
__global__ void wsplit(const float* __restrict__ Wf, ushort* __restrict__ Whi,
                       ushort* __restrict__ Wlo) {
    const int idx = blockIdx.x * 256 + threadIdx.x;     // 2*512*128 = 131072
    if (idx >= 2 * 512 * DIM) return;
    const int l = idx >> 16;
    const int rem = idx & 65535;
    const int k = rem >> 7, j = rem & 127;
    const float w = Wf[idx];
    const ushort h = f2bf(w);
    const ushort lo = f2bf(w - bf2f(h));
    const int kt = k >> 5, kl = k & 31, kg = kl >> 3, e = kl & 7;
    const int ct = j >> 4, col = j & 15;
    const size_t off = (size_t)l * 65536 + ((((kt * 8 + ct) * 4 + kg) * 16 + col) * 8 + e);
    Whi[off] = h;
    Wlo[off] = lo;
}

// ---------------------------------------------------------------------------
// 1c. fp32 -> bf16 table conversion (coalesced; only needed for feats)
// ---------------------------------------------------------------------------
__global__ __launch_bounds__(256) void h2bf(const float* __restrict__ in,
                                            ushort* __restrict__ out) {
    const int i = (blockIdx.x * 256 + threadIdx.x) * 4;   // NNODES*DIM/4 threads
    if (i >= NNODES * DIM) return;
    const float4 v = *reinterpret_cast<const float4*>(in + i);
    ushort4 o;
    o.x = f2bf(v.x); o.y = f2bf(v.y); o.z = f2bf(v.z); o.w = f2bf(v.w);
    *reinterpret_cast<ushort4*>(out + i) = o;
}

// ---------------------------------------------------------------------------
// 2. Zero-global-atomic CSR build: two-level counting sort by dst.
//    All atomics are LDS-scope; all global writes coalesced or L2-local.
// ---------------------------------------------------------------------------
// 2a. per-chunk coarse histogram (bucket = dst>>8)
__global__ __launch_bounds__(256) void hist_bkt(const int* __restrict__ dst,
                                                int* __restrict__ hist) {
    const int c = blockIdx.x, r = blockIdx.y;
    __shared__ int h[NBKT];
    for (int t = threadIdx.x; t < NBKT; t += 256) h[t] = 0;
    __syncthreads();
    #pragma unroll
    for (int u = 0; u < 8; ++u) {
        const int e = c * 2048 + u * 256 + threadIdx.x;
        if (e < NEDGE) atomicAdd(&h[dst[(size_t)r * NEDGE + e] >> 8], 1);
    }
    __syncthreads();
    for (int t = threadIdx.x; t < NBKT; t += 256)
        hist[((size_t)r * CH + c) * NBKT + t] = h[t];
}

// 2b. per-bucket scan over chunks: hist -> per-chunk exclusive offsets, tot[r][b]
__global__ __launch_bounds__(512) void scan_hist(int* __restrict__ hist,
                                                 int* __restrict__ tot) {
    const int b = blockIdx.x, r = blockIdx.y, t = threadIdx.x;
    __shared__ int s[512];
    const int v = (t < CH) ? hist[((size_t)r * CH + t) * NBKT + b] : 0;
    s[t] = v;
    __syncthreads();
    for (int off = 1; off < 512; off <<= 1) {
        const int u = (t >= off) ? s[t - off] : 0;
        __syncthreads();
        s[t] += u;
        __syncthreads();
    }
    if (t < CH) hist[((size_t)r * CH + t) * NBKT + b] = s[t] - v;   // exclusive
    if (t == 511) tot[r * NBKT + b] = s[511];
}

// 2c. exclusive scan of bucket totals -> bucket bases (relation-local)
__global__ __launch_bounds__(256) void scan_tot(const int* __restrict__ tot,
                                                int* __restrict__ bktbase) {
    const int r = blockIdx.x, t = threadIdx.x;
    __shared__ int s[256];
    const int v = (t < NBKT) ? tot[r * NBKT + t] : 0;
    s[t] = v;
    __syncthreads();
    for (int off = 1; off < 256; off <<= 1) {
        const int u = (t >= off) ? s[t - off] : 0;
        __syncthreads();
        s[t] += u;
        __syncthreads();
    }
    if (t < NBKT) bktbase[r * NBKT + t] = s[t] - v;
}

// 2d. scatter edges into bucket-sorted order, packed (src<<8)|(dst&255)
__global__ __launch_bounds__(256) void scatter_bkt(const int* __restrict__ src,
                                                   const int* __restrict__ dst,
                                                   const int* __restrict__ hist,
                                                   const int* __restrict__ bktbase,
                                                   unsigned* __restrict__ pk) {
    const int c = blockIdx.x, r = blockIdx.y;
    __shared__ int off[NBKT];
    for (int t = threadIdx.x; t < NBKT; t += 256)
        off[t] = bktbase[r * NBKT + t] + hist[((size_t)r * CH + c) * NBKT + t];
    __syncthreads();
    #pragma unroll
    for (int u = 0; u < 8; ++u) {
        const int e = c * 2048 + u * 256 + threadIdx.x;
        if (e < NEDGE) {
            const int d = dst[(size_t)r * NEDGE + e];
            const int s = src[(size_t)r * NEDGE + e];
            const int p = atomicAdd(&off[d >> 8], 1);
            pk[(size_t)r * NEDGE + p] = ((unsigned)s << 8) | (unsigned)(d & 255);
        }
    }
}

// 2e. per-bucket exact CSR: LDS count -> LDS scan -> rptr/deg/col
__global__ __launch_bounds__(256) void build_csr(const unsigned* __restrict__ pk,
                                                 const int* __restrict__ tot,
                                                 const int* __restrict__ bktbase,
                                                 int* __restrict__ rptrg,
                                                 int* __restrict__ degg,
                                                 int* __restrict__ colg) {
    const int b = blockIdx.x, r = blockIdx.y, t = threadIdx.x;
    const int ebase = bktbase[r * NBKT + b];
    const int ecnt  = tot[r * NBKT + b];
    const unsigned* p = pk + (size_t)r * NEDGE + ebase;
    __shared__ int cnt[256], loc[256], run[256];
    cnt[t] = 0;
    __syncthreads();
    for (int i = t; i < ecnt; i += 256) atomicAdd(&cnt[p[i] & 255], 1);
    __syncthreads();
    const int v = cnt[t];
    loc[t] = v;
    __syncthreads();
    for (int off = 1; off < 256; off <<= 1) {
        const int u = (t >= off) ? loc[t - off] : 0;
        __syncthreads();
        loc[t] += u;
        __syncthreads();
    }
    const int excl = loc[t] - v;
    const int node = b * 256 + t;
    if (node < NNODES) {
        degg[r * NNODES + node]  = v;
        rptrg[r * NNODES + node] = ebase + excl;    // relation-local col index
    }
    run[t] = excl;
    __syncthreads();
    for (int i = t; i < ecnt; i += 256) {
        const unsigned w = p[i];
        const int q = atomicAdd(&run[w & 255], 1);
        colg[(size_t)r * NEDGE + ebase + q] = (int)(w >> 8);
    }
}

// ---------------------------------------------------------------------------
// 3. Pull aggregation over the bf16 table: one wave per (node, relation).
//    CSR (exact degree, any size). Half-wave per edge-row (32 x ushort4 =
//    256B); 8 independent 8B loads in flight per half-wave; fp32 accumulate.
// ---------------------------------------------------------------------------
__global__ __launch_bounds__(256) void aggregate(const ushort* __restrict__ H,
                                                 const int* __restrict__ rptrg,
                                                 const int* __restrict__ degg,
                                                 const int* __restrict__ colg,
                                                 ushort* __restrict__ Xm) {
    const int wid = (blockIdx.x * 256 + threadIdx.x) >> 6;
    const int lane = threadIdx.x & 63;
    if (wid >= NREL * NNODES) return;
    const int r = wid / NNODES;
    const int n = wid - r * NNODES;
    const int e0 = rptrg[wid];
    const int dg = degg[wid];
    const int* cl = colg + (size_t)r * NEDGE + e0;
    const int hi = lane >> 5;
    const int hl = lane & 31;
    float4 acc = make_float4(0.f, 0.f, 0.f, 0.f);
    for (int base = 0; base < dg; base += 64) {
        const int ce = (base + lane < dg) ? cl[base + lane] : 0;
        const int cnt = min(64, dg - base);
        for (int j = 0; j < cnt; j += 16) {
            int   sidx[8];
            float msk[8];
            #pragma unroll
            for (int u = 0; u < 8; ++u) {
                const int eid = j + 2 * u + hi;          // <= 63 by construction
                sidx[u] = __shfl(ce, eid);
                msk[u] = (eid < cnt) ? 1.f : 0.f;
            }
            #pragma unroll
            for (int u = 0; u < 8; ++u) {
                const ushort4 v = *reinterpret_cast<const ushort4*>(
                    H + (size_t)sidx[u] * DIM + 4 * hl);
                acc.x += bf2f(v.x) * msk[u]; acc.y += bf2f(v.y) * msk[u];
                acc.z += bf2f(v.z) * msk[u]; acc.w += bf2f(v.w) * msk[u];
            }
        }
    }
    acc.x += __shfl_xor(acc.x, 32);
    acc.y += __shfl_xor(acc.y, 32);
    acc.z += __shfl_xor(acc.z, 32);
    acc.w += __shfl_xor(acc.w, 32);
    if (hi == 0) {
        const float inv = 1.f / (float)max(dg, 1);
        ushort4 o;
        o.x = f2bf(acc.x * inv); o.y = f2bf(acc.y * inv);
        o.z = f2bf(acc.z * inv); o.w = f2bf(acc.w * inv);
        *reinterpret_cast<ushort4*>(Xm + (size_t)n * (NREL * DIM) + r * DIM + 4 * hl) = o;
    }
}

// ---------------------------------------------------------------------------
// 4. Split-bf16 MFMA GEMM:  Out = act( [Hsrc | Xm] (Nx512) @ Wf (512x128) + b )
//    Self cols (kt<4, fp32 src):  Xhi@Whi + Xlo@Whi + Xhi@Wlo   (3 MFMAs)
//    Mean cols (kt>=4, bf16 src): X@Whi + X@Wlo                 (2 MFMAs)
//    No LDS, no barriers. In-place safe. WRITEBF fuses next layer's h2bf.
// ---------------------------------------------------------------------------
template <bool RELU, bool WRITEBF>
__global__ __launch_bounds__(256) void gemm_mfma(const float* __restrict__ Hsrc,
                                                 const ushort* __restrict__ Xm,
                                                 const ushort* __restrict__ Whi,
                                                 const ushort* __restrict__ Wlo,
                                                 const float* __restrict__ bias,
                                                 float* __restrict__ Out,
                                                 ushort* __restrict__ OutBf) {
    const int wave = threadIdx.x >> 6;
    const int lane = threadIdx.x & 63;
    const int r16 = lane & 15;
    const int kg  = lane >> 4;                       // 0..3
    const int wbase = blockIdx.x * 128 + wave * 32;  // wave's 32 rows

    f32x4 acc[2][8];
    #pragma unroll
    for (int t = 0; t < 2; ++t)
        #pragma unroll
        for (int ct = 0; ct < 8; ++ct) acc[t][ct] = (f32x4)0.0f;

    int rowc[2];
    #pragma unroll
    for (int t = 0; t < 2; ++t) {
        int row = wbase + t * 16 + r16;
        rowc[t] = row < NNODES ? row : NNODES - 1;   // clamp; tail rows never stored
    }

    // ---- kt 0..3: self columns from fp32 Hsrc, hi/lo split (3 MFMAs)
    for (int kt = 0; kt < 4; ++kt) {
        const int kbase = kt * 32 + kg * 8;
        bf16x8 ahi[2], alo[2];
        #pragma unroll
        for (int t = 0; t < 2; ++t) {
            const float* sp = Hsrc + (size_t)rowc[t] * DIM + kbase;
            const float4 v0 = *reinterpret_cast<const float4*>(sp);
            const float4 v1 = *reinterpret_cast<const float4*>(sp + 4);
            const float xs[8] = {v0.x, v0.y, v0.z, v0.w, v1.x, v1.y, v1.z, v1.w};
            #pragma unroll
            for (int e = 0; e < 8; ++e) {
                const float x = xs[e];
                const ushort h = f2bf(x);
                ahi[t][e] = (short)h;
                alo[t][e] = (short)f2bf(x - bf2f(h));   // Sterbenz: subtraction exact
            }
        }
        const ushort* bp  = Whi + (size_t)(kt * 8) * 512 + kg * 128 + r16 * 8;
        const ushort* bpl = Wlo + (size_t)(kt * 8) * 512 + kg * 128 + r16 * 8;
        #pragma unroll
        for (int ct = 0; ct < 8; ++ct) {
            const bf16x8 bhi = *reinterpret_cast<const bf16x8*>(bp + ct * 512);
            const bf16x8 blo = *reinterpret_cast<const bf16x8*>(bpl + ct * 512);
            #pragma unroll
            for (int t = 0; t < 2; ++t) {
                acc[t][ct] = __builtin_amdgcn_mfma_f32_16x16x32_bf16(ahi[t], bhi, acc[t][ct], 0, 0, 0);
                acc[t][ct] = __builtin_amdgcn_mfma_f32_16x16x32_bf16(alo[t], bhi, acc[t][ct], 0, 0, 0);
                acc[t][ct] = __builtin_amdgcn_mfma_f32_16x16x32_bf16(ahi[t], blo, acc[t][ct], 0, 0, 0);
            }
        }
    }
    // ---- kt 4..15: mean columns from bf16 Xm, direct A-frag load (2 MFMAs)
    for (int kt = 4; kt < 16; ++kt) {
        const int kbase = kt * 32 + kg * 8 - DIM;    // offset within Xm row
        bf16x8 a[2];
        #pragma unroll
        for (int t = 0; t < 2; ++t)
            a[t] = *reinterpret_cast<const bf16x8*>(Xm + (size_t)rowc[t] * (NREL * DIM) + kbase);
        const ushort* bp  = Whi + (size_t)(kt * 8) * 512 + kg * 128 + r16 * 8;
        const ushort* bpl = Wlo + (size_t)(kt * 8) * 512 + kg * 128 + r16 * 8;
        #pragma unroll
        for (int ct = 0; ct < 8; ++ct) {
            const bf16x8 bhi = *reinterpret_cast<const bf16x8*>(bp + ct * 512);
            const bf16x8 blo = *reinterpret_cast<const bf16x8*>(bpl + ct * 512);
            #pragma unroll
            for (int t = 0; t < 2; ++t) {
                acc[t][ct] = __builtin_amdgcn_mfma_f32_16x16x32_bf16(a[t], bhi, acc[t][ct], 0, 0, 0);
                acc[t][ct] = __builtin_amdgcn_mfma_f32_16x16x32_bf16(a[t], blo, acc[t][ct], 0, 0, 0);
            }
        }
    }
    // epilogue: bias + optional ReLU + store (fp32, and bf16 copy if WRITEBF)
    float bias_r[8];
    #pragma unroll
    for (int ct = 0; ct < 8; ++ct) bias_r[ct] = bias[ct * 16 + r16];
    #pragma unroll
    for (int t = 0; t < 2; ++t) {
        #pragma unroll
        for (int q = 0; q < 4; ++q) {
            const int row = wbase + t * 16 + kg * 4 + q;
            if (row >= NNODES) continue;
            #pragma unroll
            for (int ct = 0; ct < 8; ++ct) {
                float v = acc[t][ct][q] + bias_r[ct];
                if (RELU) v = fmaxf(v, 0.f);
                Out[(size_t)row * DIM + ct * 16 + r16] = v;
                if (WRITEBF) OutBf[(size_t)row * DIM + ct * 16 + r16] = f2bf(v);
            }
        }
    }
}

// ---------------------------------------------------------------------------
extern "C" void kernel_launch(void* const* d_in, const int* in_sizes, int n_in,
                              void* d_out, int out_size, void* d_ws, size_t ws_size,
                              hipStream_t stream) {
    const float* feats  = (const float*)d_in[0];
    const int*   src    = (const int*)d_in[1];
    const int*   dst    = (const int*)d_in[2];
    const float* Wself  = (const float*)d_in[3];
    const float* bself  = (const float*)d_in[4];
    const float* Wneigh = (const float*)d_in[5];
    const float* Wm     = (const float*)d_in[6];
    const float* bmv    = (const float*)d_in[7];
    float* out = (float*)d_out;

    // workspace carve-up (4-byte words); H1 lives in d_out (in-place layer 1)
    float* ws      = (float*)d_ws;
    float* Wf      = ws;                          // 131072
    float* bias    = Wf + 131072;                 // 256
    int*   hist    = (int*)(bias + 256);          // 3*391*196 = 229908 -> pad 230016
    int*   tot     = hist + 230016;               // 3*196 = 588 -> pad 640
    int*   bktbase = tot + 640;                   // 640
    int*   rptrg   = bktbase + 640;               // 150000
    int*   degg    = rptrg + 150000;              // 150000
    unsigned* pk   = (unsigned*)(degg + 150000);  // 2400000
    int*   colg    = (int*)(pk + 2400000);        // 2400000
    ushort* Whi    = (ushort*)(colg + 2400000);   // 131072 u16 = 65536 words
    ushort* Wlo    = Whi + 131072;                // 65536 words
    ushort* Fbf    = Wlo + 131072;                // N*128 u16 = 3200000 words
    ushort* Xm     = Fbf + 6400000;               // N*384 u16 = 9600000 words
    float* H1      = out;
    // total ~= 74 MB

    prep_weights<<<dim3(513, 2), 128, 0, stream>>>(Wself, bself, Wneigh, Wm, bmv, Wf, bias);
    wsplit<<<512, 256, 0, stream>>>(Wf, Whi, Wlo);

    // CSR build (zero global atomics; built once, used by both layers)
    hist_bkt<<<dim3(CH, NREL), 256, 0, stream>>>(dst, hist);
    scan_hist<<<dim3(NBKT, NREL), 512, 0, stream>>>(hist, tot);
    scan_tot<<<NREL, 256, 0, stream>>>(tot, bktbase);
    scatter_bkt<<<dim3(CH, NREL), 256, 0, stream>>>(src, dst, hist, bktbase, pk);
    build_csr<<<dim3(NBKT, NREL), 256, 0, stream>>>(pk, tot, bktbase, rptrg, degg, colg);

    const int aggBlocks  = (NREL * NNODES) / 4;          // 4 waves/block, exact
    const int gemmBlocks = (NNODES + 127) / 128;         // 391
    const int cvtBlocks  = (NNODES * DIM) / 4 / 256;     // 6250, exact

    // layer 0  (GEMM also emits bf16 H1 -> Fbf, fusing layer-1's h2bf)
    h2bf<<<cvtBlocks, 256, 0, stream>>>(feats, Fbf);
    aggregate<<<aggBlocks, 256, 0, stream>>>(Fbf, rptrg, degg, colg, Xm);
    gemm_mfma<true, true><<<gemmBlocks, 256, 0, stream>>>(feats, Xm, Whi, Wlo, bias, H1, Fbf);

    // layer 1 (in place: Hsrc == Out == d_out)
    aggregate<<<aggBlocks, 256, 0, stream>>>(Fbf, rptrg, degg, colg, Xm);
    gemm_mfma<false, false><<<gemmBlocks, 256, 0, stream>>>(H1, Xm, Whi + 65536, Wlo + 65536,
                                                            bias + 128, out, Fbf);
}

// Round 11
// 395.724 us; speedup vs baseline: 2.1755x; 1.0274x over previous
//
#include <hip/hip_runtime.h>
#include <hip/hip_bf16.h>

#define NNODES 50000
#define DIM 128
#define NREL 3
#define NEDGE 800000
#define NBKT 196             // ceil(NNODES/256) coarse buckets (dst>>8)
#define CH 391               // ceil(NEDGE/2048) edge chunks
// K of the fused GEMM = DIM (self) + NREL*DIM (means) = 512

typedef __attribute__((ext_vector_type(8))) short bf16x8;     // 8 bf16 in 4 VGPRs
typedef __attribute__((ext_vector_type(4))) float f32x4;      // MFMA accumulator
typedef __attribute__((ext_vector_type(8))) unsigned short ushortx8;

__device__ __forceinline__ ushort f2bf(float x) {             // RNE fp32->bf16
    unsigned u = __float_as_uint(x);
    return (ushort)((u + 0x7fffu + ((u >> 16) & 1u)) >> 16);
}
__device__ __forceinline__ float bf2f(ushort h) {
    return __uint_as_float(((unsigned)h) << 16);
}

// ---------------------------------------------------------------------------
// 1. Fold weights AND split hi/lo bf16 in MFMA B-fragment order (fused):
//    Wf[l](512x128) = [ W_self@S ; W_neigh@Wm_0 ; W_neigh@Wm_1 ; W_neigh@Wm_2 ],
//    S = sum_r Wm_r;  bias c[l] = b_self@S + bm.
//    frag off = (((kt*8+ct)*4+kg)*16+col)*8 + e  (kt=i>>5,kg=(i&31)>>3,e=i&7,
//    ct=j>>4,col=j&15) — matches gemm_mfma's dwordx4 B-frag reads.
// ---------------------------------------------------------------------------
__global__ void prep_wsplit(const float* __restrict__ Wself, const float* __restrict__ bself,
                            const float* __restrict__ Wneigh, const float* __restrict__ Wm,
                            const float* __restrict__ bm,
                            ushort* __restrict__ Whi, ushort* __restrict__ Wlo,
                            float* __restrict__ bias) {
    const int l = blockIdx.y;
    const int i = blockIdx.x;          // 0..512 (512 => bias row)
    const int j = threadIdx.x;         // 0..127
    const float* Wm_l = Wm + (size_t)l * 3 * DIM * DIM;
    if (i == 512) {
        float acc = bm[l * DIM + j];
        for (int k = 0; k < DIM; ++k) {
            float s = Wm_l[k * DIM + j] + Wm_l[(DIM + k) * DIM + j] + Wm_l[(2 * DIM + k) * DIM + j];
            acc += bself[l * DIM + k] * s;
        }
        bias[l * DIM + j] = acc;
        return;
    }
    float acc = 0.f;
    if (i < DIM) {                     // W_self @ S
        const float* A = Wself + (size_t)l * DIM * DIM + (size_t)i * DIM;
        for (int k = 0; k < DIM; ++k) {
            float s = Wm_l[k * DIM + j] + Wm_l[(DIM + k) * DIM + j] + Wm_l[(2 * DIM + k) * DIM + j];
            acc += A[k] * s;
        }
    } else {                           // W_neigh @ Wm_r  (row a of block r)
        const int r = (i - DIM) >> 7;
        const int a = (i - DIM) & 127;
        const float* A = Wneigh + (size_t)l * DIM * DIM + (size_t)a * DIM;
        const float* B = Wm_l + (size_t)r * DIM * DIM;
        for (int k = 0; k < DIM; ++k) acc += A[k] * B[k * DIM + j];
    }
    const ushort h  = f2bf(acc);
    const ushort lo = f2bf(acc - bf2f(h));
    const int kt = i >> 5, kl = i & 31, kg = kl >> 3, e = kl & 7;
    const int ct = j >> 4, col = j & 15;
    const size_t off = (size_t)l * 65536 + ((((kt * 8 + ct) * 4 + kg) * 16 + col) * 8 + e);
    Whi[off] = h;
    Wlo[off] = lo;
}

// ---------------------------------------------------------------------------
// 1c. fp32 -> bf16 table conversion (coalesced; only needed for feats)
// ---------------------------------------------------------------------------
__global__ __launch_bounds__(256) void h2bf(const float* __restrict__ in,
                                            ushort* __restrict__ out) {
    const int i = (blockIdx.x * 256 + threadIdx.x) * 4;   // NNODES*DIM/4 threads
    if (i >= NNODES * DIM) return;
    const float4 v = *reinterpret_cast<const float4*>(in + i);
    ushort4 o;
    o.x = f2bf(v.x); o.y = f2bf(v.y); o.z = f2bf(v.z); o.w = f2bf(v.w);
    *reinterpret_cast<ushort4*>(out + i) = o;
}

// ---------------------------------------------------------------------------
// 2. Zero-global-atomic CSR build: two-level counting sort by dst.
// ---------------------------------------------------------------------------
__global__ __launch_bounds__(256) void hist_bkt(const int* __restrict__ dst,
                                                int* __restrict__ hist) {
    const int c = blockIdx.x, r = blockIdx.y;
    __shared__ int h[NBKT];
    for (int t = threadIdx.x; t < NBKT; t += 256) h[t] = 0;
    __syncthreads();
    #pragma unroll
    for (int u = 0; u < 8; ++u) {
        const int e = c * 2048 + u * 256 + threadIdx.x;
        if (e < NEDGE) atomicAdd(&h[dst[(size_t)r * NEDGE + e] >> 8], 1);
    }
    __syncthreads();
    for (int t = threadIdx.x; t < NBKT; t += 256)
        hist[((size_t)r * CH + c) * NBKT + t] = h[t];
}

__global__ __launch_bounds__(512) void scan_hist(int* __restrict__ hist,
                                                 int* __restrict__ tot) {
    const int b = blockIdx.x, r = blockIdx.y, t = threadIdx.x;
    __shared__ int s[512];
    const int v = (t < CH) ? hist[((size_t)r * CH + t) * NBKT + b] : 0;
    s[t] = v;
    __syncthreads();
    for (int off = 1; off < 512; off <<= 1) {
        const int u = (t >= off) ? s[t - off] : 0;
        __syncthreads();
        s[t] += u;
        __syncthreads();
    }
    if (t < CH) hist[((size_t)r * CH + t) * NBKT + b] = s[t] - v;   // exclusive
    if (t == 511) tot[r * NBKT + b] = s[511];
}

__global__ __launch_bounds__(256) void scan_tot(const int* __restrict__ tot,
                                                int* __restrict__ bktbase) {
    const int r = blockIdx.x, t = threadIdx.x;
    __shared__ int s[256];
    const int v = (t < NBKT) ? tot[r * NBKT + t] : 0;
    s[t] = v;
    __syncthreads();
    for (int off = 1; off < 256; off <<= 1) {
        const int u = (t >= off) ? s[t - off] : 0;
        __syncthreads();
        s[t] += u;
        __syncthreads();
    }
    if (t < NBKT) bktbase[r * NBKT + t] = s[t] - v;
}

__global__ __launch_bounds__(256) void scatter_bkt(const int* __restrict__ src,
                                                   const int* __restrict__ dst,
                                                   const int* __restrict__ hist,
                                                   const int* __restrict__ bktbase,
                                                   unsigned* __restrict__ pk) {
    const int c = blockIdx.x, r = blockIdx.y;
    __shared__ int off[NBKT];
    for (int t = threadIdx.x; t < NBKT; t += 256)
        off[t] = bktbase[r * NBKT + t] + hist[((size_t)r * CH + c) * NBKT + t];
    __syncthreads();
    #pragma unroll
    for (int u = 0; u < 8; ++u) {
        const int e = c * 2048 + u * 256 + threadIdx.x;
        if (e < NEDGE) {
            const int d = dst[(size_t)r * NEDGE + e];
            const int s = src[(size_t)r * NEDGE + e];
            const int p = atomicAdd(&off[d >> 8], 1);
            pk[(size_t)r * NEDGE + p] = ((unsigned)s << 8) | (unsigned)(d & 255);
        }
    }
}

__global__ __launch_bounds__(256) void build_csr(const unsigned* __restrict__ pk,
                                                 const int* __restrict__ tot,
                                                 const int* __restrict__ bktbase,
                                                 int* __restrict__ rptrg,
                                                 int* __restrict__ degg,
                                                 int* __restrict__ colg) {
    const int b = blockIdx.x, r = blockIdx.y, t = threadIdx.x;
    const int ebase = bktbase[r * NBKT + b];
    const int ecnt  = tot[r * NBKT + b];
    const unsigned* p = pk + (size_t)r * NEDGE + ebase;
    __shared__ int cnt[256], loc[256], run[256];
    cnt[t] = 0;
    __syncthreads();
    for (int i = t; i < ecnt; i += 256) atomicAdd(&cnt[p[i] & 255], 1);
    __syncthreads();
    const int v = cnt[t];
    loc[t] = v;
    __syncthreads();
    for (int off = 1; off < 256; off <<= 1) {
        const int u = (t >= off) ? loc[t - off] : 0;
        __syncthreads();
        loc[t] += u;
        __syncthreads();
    }
    const int excl = loc[t] - v;
    const int node = b * 256 + t;
    if (node < NNODES) {
        degg[r * NNODES + node]  = v;
        rptrg[r * NNODES + node] = ebase + excl;    // relation-local col index
    }
    run[t] = excl;
    __syncthreads();
    for (int i = t; i < ecnt; i += 256) {
        const unsigned w = p[i];
        const int q = atomicAdd(&run[w & 255], 1);
        colg[(size_t)r * NEDGE + ebase + q] = (int)(w >> 8);
    }
}

// ---------------------------------------------------------------------------
// 3. Pull aggregation, quarter-wave layout: one wave per (node, relation);
//    16 lanes cover a 256B row (dwordx4 each); 4 edges in flight per wave.
//    Unmasked full-16 edge blocks + masked tail (modal deg=16 is unmasked).
//    Shfl pre-scaled byte offsets; bf16->f32 via and/shl; fp32 accumulate.
// ---------------------------------------------------------------------------
__global__ __launch_bounds__(256) void aggregate(const ushort* __restrict__ H,
                                                 const int* __restrict__ rptrg,
                                                 const int* __restrict__ degg,
                                                 const int* __restrict__ colg,
                                                 ushort* __restrict__ Xm) {
    const int wid = (blockIdx.x * 256 + threadIdx.x) >> 6;
    const int lane = threadIdx.x & 63;
    if (wid >= NREL * NNODES) return;
    const int r = wid / NNODES;
    const int n = wid - r * NNODES;
    const int e0 = rptrg[wid];
    const int dg = degg[wid];
    const int* cl = colg + (size_t)r * NEDGE + e0;
    const int es = lane >> 4;            // edge slot 0..3
    const int q  = lane & 15;            // col group: cols [8q..8q+8)
    const char* Hb = (const char*)H + q * 16;
    float a0 = 0.f, a1 = 0.f, a2 = 0.f, a3 = 0.f,
          a4 = 0.f, a5 = 0.f, a6 = 0.f, a7 = 0.f;
    for (int base = 0; base < dg; base += 64) {
        const int idx = base + lane;
        const int boff = (idx < dg) ? (cl[idx] << 8) : 0;    // row byte offset
        const int cnt = min(64, dg - base);
        int j = 0;
        for (; j + 16 <= cnt; j += 16) {                     // unmasked full blocks
            #pragma unroll
            for (int u = 0; u < 4; ++u) {
                const int ro = __shfl(boff, j + 4 * u + es);
                const uint4 w = *reinterpret_cast<const uint4*>(Hb + ro);
                a0 += __uint_as_float(w.x << 16);
                a1 += __uint_as_float(w.x & 0xffff0000u);
                a2 += __uint_as_float(w.y << 16);
                a3 += __uint_as_float(w.y & 0xffff0000u);
                a4 += __uint_as_float(w.z << 16);
                a5 += __uint_as_float(w.z & 0xffff0000u);
                a6 += __uint_as_float(w.w << 16);
                a7 += __uint_as_float(w.w & 0xffff0000u);
            }
        }
        if (j < cnt) {                                       // masked tail
            #pragma unroll
            for (int u = 0; u < 4; ++u) {
                const int eid = j + 4 * u + es;
                const int ro = __shfl(boff, eid);
                const float m = (eid < cnt) ? 1.f : 0.f;
                const uint4 w = *reinterpret_cast<const uint4*>(Hb + ro);
                a0 = fmaf(__uint_as_float(w.x << 16), m, a0);
                a1 = fmaf(__uint_as_float(w.x & 0xffff0000u), m, a1);
                a2 = fmaf(__uint_as_float(w.y << 16), m, a2);
                a3 = fmaf(__uint_as_float(w.y & 0xffff0000u), m, a3);
                a4 = fmaf(__uint_as_float(w.z << 16), m, a4);
                a5 = fmaf(__uint_as_float(w.z & 0xffff0000u), m, a5);
                a6 = fmaf(__uint_as_float(w.w << 16), m, a6);
                a7 = fmaf(__uint_as_float(w.w & 0xffff0000u), m, a7);
            }
        }
    }
    // reduce across the 4 edge slots (lanes q, q+16, q+32, q+48)
    a0 += __shfl_xor(a0, 16); a1 += __shfl_xor(a1, 16);
    a2 += __shfl_xor(a2, 16); a3 += __shfl_xor(a3, 16);
    a4 += __shfl_xor(a4, 16); a5 += __shfl_xor(a5, 16);
    a6 += __shfl_xor(a6, 16); a7 += __shfl_xor(a7, 16);
    a0 += __shfl_xor(a0, 32); a1 += __shfl_xor(a1, 32);
    a2 += __shfl_xor(a2, 32); a3 += __shfl_xor(a3, 32);
    a4 += __shfl_xor(a4, 32); a5 += __shfl_xor(a5, 32);
    a6 += __shfl_xor(a6, 32); a7 += __shfl_xor(a7, 32);
    if (es == 0) {
        const float inv = 1.f / (float)max(dg, 1);
        ushortx8 o;
        o[0] = f2bf(a0 * inv); o[1] = f2bf(a1 * inv);
        o[2] = f2bf(a2 * inv); o[3] = f2bf(a3 * inv);
        o[4] = f2bf(a4 * inv); o[5] = f2bf(a5 * inv);
        o[6] = f2bf(a6 * inv); o[7] = f2bf(a7 * inv);
        *reinterpret_cast<ushortx8*>(Xm + (size_t)n * (NREL * DIM) + r * DIM + q * 8) = o;
    }
}

// ---------------------------------------------------------------------------
// 4. Split-bf16 MFMA GEMM:  Out = act( [Hsrc | Xm] (Nx512) @ Wf (512x128) + b )
//    Self cols (kt<4, fp32 src):  Xhi@Whi + Xlo@Whi + Xhi@Wlo   (3 MFMAs)
//    Mean cols (kt>=4, bf16 src): X@Whi + X@Wlo                 (2 MFMAs)
//    No LDS, no barriers. In-place safe. WRITEBF fuses next layer's h2bf.
// ---------------------------------------------------------------------------
template <bool RELU, bool WRITEBF>
__global__ __launch_bounds__(256) void gemm_mfma(const float* __restrict__ Hsrc,
                                                 const ushort* __restrict__ Xm,
                                                 const ushort* __restrict__ Whi,
                                                 const ushort* __restrict__ Wlo,
                                                 const float* __restrict__ bias,
                                                 float* __restrict__ Out,
                                                 ushort* __restrict__ OutBf) {
    const int wave = threadIdx.x >> 6;
    const int lane = threadIdx.x & 63;
    const int r16 = lane & 15;
    const int kg  = lane >> 4;                       // 0..3
    const int wbase = blockIdx.x * 128 + wave * 32;  // wave's 32 rows

    f32x4 acc[2][8];
    #pragma unroll
    for (int t = 0; t < 2; ++t)
        #pragma unroll
        for (int ct = 0; ct < 8; ++ct) acc[t][ct] = (f32x4)0.0f;

    int rowc[2];
    #pragma unroll
    for (int t = 0; t < 2; ++t) {
        int row = wbase + t * 16 + r16;
        rowc[t] = row < NNODES ? row : NNODES - 1;   // clamp; tail rows never stored
    }

    // ---- kt 0..3: self columns from fp32 Hsrc, hi/lo split (3 MFMAs)
    for (int kt = 0; kt < 4; ++kt) {
        const int kbase = kt * 32 + kg * 8;
        bf16x8 ahi[2], alo[2];
        #pragma unroll
        for (int t = 0; t < 2; ++t) {
            const float* sp = Hsrc + (size_t)rowc[t] * DIM + kbase;
            const float4 v0 = *reinterpret_cast<const float4*>(sp);
            const float4 v1 = *reinterpret_cast<const float4*>(sp + 4);
            const float xs[8] = {v0.x, v0.y, v0.z, v0.w, v1.x, v1.y, v1.z, v1.w};
            #pragma unroll
            for (int e = 0; e < 8; ++e) {
                const float x = xs[e];
                const ushort h = f2bf(x);
                ahi[t][e] = (short)h;
                alo[t][e] = (short)f2bf(x - bf2f(h));   // Sterbenz: subtraction exact
            }
        }
        const ushort* bp  = Whi + (size_t)(kt * 8) * 512 + kg * 128 + r16 * 8;
        const ushort* bpl = Wlo + (size_t)(kt * 8) * 512 + kg * 128 + r16 * 8;
        #pragma unroll
        for (int ct = 0; ct < 8; ++ct) {
            const bf16x8 bhi = *reinterpret_cast<const bf16x8*>(bp + ct * 512);
            const bf16x8 blo = *reinterpret_cast<const bf16x8*>(bpl + ct * 512);
            #pragma unroll
            for (int t = 0; t < 2; ++t) {
                acc[t][ct] = __builtin_amdgcn_mfma_f32_16x16x32_bf16(ahi[t], bhi, acc[t][ct], 0, 0, 0);
                acc[t][ct] = __builtin_amdgcn_mfma_f32_16x16x32_bf16(alo[t], bhi, acc[t][ct], 0, 0, 0);
                acc[t][ct] = __builtin_amdgcn_mfma_f32_16x16x32_bf16(ahi[t], blo, acc[t][ct], 0, 0, 0);
            }
        }
    }
    // ---- kt 4..15: mean columns from bf16 Xm, direct A-frag load (2 MFMAs)
    for (int kt = 4; kt < 16; ++kt) {
        const int kbase = kt * 32 + kg * 8 - DIM;    // offset within Xm row
        bf16x8 a[2];
        #pragma unroll
        for (int t = 0; t < 2; ++t)
            a[t] = *reinterpret_cast<const bf16x8*>(Xm + (size_t)rowc[t] * (NREL * DIM) + kbase);
        const ushort* bp  = Whi + (size_t)(kt * 8) * 512 + kg * 128 + r16 * 8;
        const ushort* bpl = Wlo + (size_t)(kt * 8) * 512 + kg * 128 + r16 * 8;
        #pragma unroll
        for (int ct = 0; ct < 8; ++ct) {
            const bf16x8 bhi = *reinterpret_cast<const bf16x8*>(bp + ct * 512);
            const bf16x8 blo = *reinterpret_cast<const bf16x8*>(bpl + ct * 512);
            #pragma unroll
            for (int t = 0; t < 2; ++t) {
                acc[t][ct] = __builtin_amdgcn_mfma_f32_16x16x32_bf16(a[t], bhi, acc[t][ct], 0, 0, 0);
                acc[t][ct] = __builtin_amdgcn_mfma_f32_16x16x32_bf16(a[t], blo, acc[t][ct], 0, 0, 0);
            }
        }
    }
    // epilogue: bias + optional ReLU + store (fp32, and bf16 copy if WRITEBF)
    float bias_r[8];
    #pragma unroll
    for (int ct = 0; ct < 8; ++ct) bias_r[ct] = bias[ct * 16 + r16];
    #pragma unroll
    for (int t = 0; t < 2; ++t) {
        #pragma unroll
        for (int q = 0; q < 4; ++q) {
            const int row = wbase + t * 16 + kg * 4 + q;
            if (row >= NNODES) continue;
            #pragma unroll
            for (int ct = 0; ct < 8; ++ct) {
                float v = acc[t][ct][q] + bias_r[ct];
                if (RELU) v = fmaxf(v, 0.f);
                Out[(size_t)row * DIM + ct * 16 + r16] = v;
                if (WRITEBF) OutBf[(size_t)row * DIM + ct * 16 + r16] = f2bf(v);
            }
        }
    }
}

// ---------------------------------------------------------------------------
extern "C" void kernel_launch(void* const* d_in, const int* in_sizes, int n_in,
                              void* d_out, int out_size, void* d_ws, size_t ws_size,
                              hipStream_t stream) {
    const float* feats  = (const float*)d_in[0];
    const int*   src    = (const int*)d_in[1];
    const int*   dst    = (const int*)d_in[2];
    const float* Wself  = (const float*)d_in[3];
    const float* bself  = (const float*)d_in[4];
    const float* Wneigh = (const float*)d_in[5];
    const float* Wm     = (const float*)d_in[6];
    const float* bmv    = (const float*)d_in[7];
    float* out = (float*)d_out;

    // workspace carve-up (4-byte words); H1 lives in d_out (in-place layer 1)
    float* ws      = (float*)d_ws;
    float* bias    = ws;                          // 256
    int*   hist    = (int*)(bias + 256);          // 3*391*196 = 229908 -> pad 230016
    int*   tot     = hist + 230016;               // 588 -> pad 640
    int*   bktbase = tot + 640;                   // 640
    int*   rptrg   = bktbase + 640;               // 150000
    int*   degg    = rptrg + 150000;              // 150000
    unsigned* pk   = (unsigned*)(degg + 150000);  // 2400000
    int*   colg    = (int*)(pk + 2400000);        // 2400000
    ushort* Whi    = (ushort*)(colg + 2400000);   // 131072 u16 = 65536 words
    ushort* Wlo    = Whi + 131072;                // 65536 words
    ushort* Fbf    = Wlo + 131072;                // N*128 u16 = 3200000 words
    ushort* Xm     = Fbf + 6400000;               // N*384 u16 = 9600000 words
    float* H1      = out;
    // total ~= 73 MB

    prep_wsplit<<<dim3(513, 2), 128, 0, stream>>>(Wself, bself, Wneigh, Wm, bmv,
                                                  Whi, Wlo, bias);

    // CSR build (zero global atomics; built once, used by both layers)
    hist_bkt<<<dim3(CH, NREL), 256, 0, stream>>>(dst, hist);
    scan_hist<<<dim3(NBKT, NREL), 512, 0, stream>>>(hist, tot);
    scan_tot<<<NREL, 256, 0, stream>>>(tot, bktbase);
    scatter_bkt<<<dim3(CH, NREL), 256, 0, stream>>>(src, dst, hist, bktbase, pk);
    build_csr<<<dim3(NBKT, NREL), 256, 0, stream>>>(pk, tot, bktbase, rptrg, degg, colg);

    const int aggBlocks  = (NREL * NNODES) / 4;          // 4 waves/block, exact
    const int gemmBlocks = (NNODES + 127) / 128;         // 391
    const int cvtBlocks  = (NNODES * DIM) / 4 / 256;     // 6250, exact

    // layer 0  (GEMM also emits bf16 H1 -> Fbf, fusing layer-1's h2bf)
    h2bf<<<cvtBlocks, 256, 0, stream>>>(feats, Fbf);
    aggregate<<<aggBlocks, 256, 0, stream>>>(Fbf, rptrg, degg, colg, Xm);
    gemm_mfma<true, true><<<gemmBlocks, 256, 0, stream>>>(feats, Xm, Whi, Wlo, bias, H1, Fbf);

    // layer 1 (in place: Hsrc == Out == d_out)
    aggregate<<<aggBlocks, 256, 0, stream>>>(Fbf, rptrg, degg, colg, Xm);
    gemm_mfma<false, false><<<gemmBlocks, 256, 0, stream>>>(H1, Xm, Whi + 65536, Wlo + 65536,
                                                            bias + 128, out, Fbf);
}